// Round 1
// baseline (212.588 us; speedup 1.0000x reference)
//
#include <hip/hip_runtime.h>
#include <cmath>

namespace {
constexpr int B = 8, N = 1024, IND = 256, OUTD = 256, H = 8, D = 32;
constexpr float NEG = -1.0e9f;
}

// ---------------------------------------------------------------------------
// K1: h[b,n,o] = sum_i x[b,n,i] * W[o,i]   (M=8192, N=256, K=256 fp32 GEMM)
// 64x64 tile, 256 threads, 4x4 micro-tile per thread.
// ---------------------------------------------------------------------------
__global__ __launch_bounds__(256) void gat_gemm(const float* __restrict__ x,
                                                const float* __restrict__ W,
                                                float* __restrict__ hout) {
  __shared__ float xs[64][17];
  __shared__ float ws[64][17];
  const int t = threadIdx.x;
  const int bm = blockIdx.x, bn = blockIdx.y;
  const int srow = t >> 2, sc = (t & 3) << 2;
  const int tx = t & 15, ty = t >> 4;
  const float* xp = x + (size_t)(bm * 64) * IND;
  const float* wp = W + (size_t)(bn * 64) * IND;
  float acc[4][4] = {};
  for (int ks = 0; ks < IND; ks += 16) {
    __syncthreads();
    float4 xv = *(const float4*)(xp + srow * IND + ks + sc);
    float4 wv = *(const float4*)(wp + srow * IND + ks + sc);
    xs[srow][sc + 0] = xv.x; xs[srow][sc + 1] = xv.y;
    xs[srow][sc + 2] = xv.z; xs[srow][sc + 3] = xv.w;
    ws[srow][sc + 0] = wv.x; ws[srow][sc + 1] = wv.y;
    ws[srow][sc + 2] = wv.z; ws[srow][sc + 3] = wv.w;
    __syncthreads();
#pragma unroll
    for (int kk = 0; kk < 16; ++kk) {
      float av[4], bv[4];
#pragma unroll
      for (int r = 0; r < 4; ++r) av[r] = xs[ty * 4 + r][kk];
#pragma unroll
      for (int c = 0; c < 4; ++c) bv[c] = ws[tx * 4 + c][kk];
#pragma unroll
      for (int r = 0; r < 4; ++r)
#pragma unroll
        for (int c = 0; c < 4; ++c) acc[r][c] += av[r] * bv[c];
    }
  }
#pragma unroll
  for (int r = 0; r < 4; ++r) {
    float4 v = make_float4(acc[r][0], acc[r][1], acc[r][2], acc[r][3]);
    *(float4*)(hout + (size_t)(bm * 64 + ty * 4 + r) * OUTD + bn * 64 + tx * 4) = v;
  }
}

// ---------------------------------------------------------------------------
// K1b: s_i[bn,h] = sum_d h[bn,h*32+d]*a_src[h,d];  s_j likewise with a_dst.
// One block per (b,n) row, 256 threads (one per output channel o).
// a layout: a[0,h,0:32]=a_src, a[0,h,32:64]=a_dst  -> flat a[h*64 + d (+32)]
// ---------------------------------------------------------------------------
__global__ __launch_bounds__(256) void gat_scores(const float* __restrict__ h,
                                                  const float* __restrict__ a,
                                                  float* __restrict__ si,
                                                  float* __restrict__ sj) {
  const int bn = blockIdx.x;
  const int t = threadIdx.x;
  const float hv = h[(size_t)bn * OUTD + t];
  const int hh = t >> 5, d = t & 31;
  float p1 = hv * a[hh * 64 + d];
  float p2 = hv * a[hh * 64 + 32 + d];
#pragma unroll
  for (int s = 16; s > 0; s >>= 1) {
    p1 += __shfl_xor(p1, s);
    p2 += __shfl_xor(p2, s);
  }
  if (d == 0) {
    si[bn * H + hh] = p1;
    sj[bn * H + hh] = p2;
  }
}

// ---------------------------------------------------------------------------
// K2: softmax stats. Block per (b,i): m[b,i,h] = max_j e, l = sum_j exp(e-m),
// with e = mask ? leakyrelu(s_i+s_j) : -1e9.
// ---------------------------------------------------------------------------
__global__ __launch_bounds__(256) void gat_stats(const int* __restrict__ adj,
                                                 const float* __restrict__ si_g,
                                                 const float* __restrict__ sj_g,
                                                 float* __restrict__ m_g,
                                                 float* __restrict__ l_g) {
  const int bi = blockIdx.x;        // b*N + i
  const int b = bi >> 10;
  const int t = threadIdx.x;
  __shared__ float red[4][H];

  float si[H];
#pragma unroll
  for (int hq = 0; hq < H; ++hq) si[hq] = si_g[bi * H + hq];

  const int* arow = adj + (size_t)bi * N;
  const float* sjb = sj_g + (size_t)b * N * H;

  int adjv[4];
  float sjv[4][H];
  float lm[H];
#pragma unroll
  for (int hq = 0; hq < H; ++hq) lm[hq] = -INFINITY;

#pragma unroll
  for (int k = 0; k < 4; ++k) {
    const int j = t + k * 256;
    adjv[k] = arow[j];
    const float4* p = (const float4*)(sjb + j * H);
    float4 u0 = p[0], u1 = p[1];
    sjv[k][0] = u0.x; sjv[k][1] = u0.y; sjv[k][2] = u0.z; sjv[k][3] = u0.w;
    sjv[k][4] = u1.x; sjv[k][5] = u1.y; sjv[k][6] = u1.z; sjv[k][7] = u1.w;
#pragma unroll
    for (int hq = 0; hq < H; ++hq) {
      float e = si[hq] + sjv[k][hq];
      e = e > 0.f ? e : 0.2f * e;
      if (adjv[k] == 0) e = NEG;
      lm[hq] = fmaxf(lm[hq], e);
    }
  }
  // wave reduce (64 lanes)
#pragma unroll
  for (int hq = 0; hq < H; ++hq)
#pragma unroll
    for (int s = 32; s > 0; s >>= 1) lm[hq] = fmaxf(lm[hq], __shfl_xor(lm[hq], s));
  const int wv = t >> 6, lane = t & 63;
  if (lane == 0)
#pragma unroll
    for (int hq = 0; hq < H; ++hq) red[wv][hq] = lm[hq];
  __syncthreads();
  float m[H];
#pragma unroll
  for (int hq = 0; hq < H; ++hq)
    m[hq] = fmaxf(fmaxf(red[0][hq], red[1][hq]), fmaxf(red[2][hq], red[3][hq]));
  __syncthreads();

  float ls[H] = {};
#pragma unroll
  for (int k = 0; k < 4; ++k) {
#pragma unroll
    for (int hq = 0; hq < H; ++hq) {
      float e = si[hq] + sjv[k][hq];
      e = e > 0.f ? e : 0.2f * e;
      if (adjv[k] == 0) e = NEG;
      ls[hq] += __expf(e - m[hq]);
    }
  }
#pragma unroll
  for (int hq = 0; hq < H; ++hq)
#pragma unroll
    for (int s = 32; s > 0; s >>= 1) ls[hq] += __shfl_xor(ls[hq], s);
  if (lane == 0)
#pragma unroll
    for (int hq = 0; hq < H; ++hq) red[wv][hq] = ls[hq];
  __syncthreads();
  if (t < H) {
    m_g[bi * H + t] = m[t];
    l_g[bi * H + t] = red[0][t] + red[1][t] + red[2][t] + red[3][t];
  }
}

// ---------------------------------------------------------------------------
// K3: aggregation. Block per (b, 32-row i-tile), 512 threads.
// Loops 32 j-tiles of 32: stage h[j-tile] (32KB) + adj tile + s_j tile;
// compute w[j][h][i] = exp(e - m) in LDS; FMA-accumulate h' per (h,d,i).
// Epilogue: /l, ELU, store.
// ---------------------------------------------------------------------------
__global__ __launch_bounds__(512) void gat_agg(const int* __restrict__ adj,
                                               const float* __restrict__ h_g,
                                               const float* __restrict__ si_g,
                                               const float* __restrict__ m_g,
                                               const float* __restrict__ sj_g,
                                               const float* __restrict__ l_g,
                                               float* __restrict__ out) {
  __shared__ float h_lds[32][256];   // [j][o]
  __shared__ float w_lds[32][8][32]; // [j][h][i]
  __shared__ int adj_lds[32][33];    // [i][j] padded
  __shared__ float sj_lds[32][8];    // [j][h]

  const int b = blockIdx.x >> 5;
  const int it = blockIdx.x & 31;
  const int i0 = it * 32;
  const int t = threadIdx.x;

  // w-compute role: (i, h, j-half)
  const int ci = t & 31, ch = (t >> 5) & 7, cjh = t >> 8;
  // FMA role: (d, h, i-half)
  const int fd = t & 31, fh = (t >> 5) & 7, fih = t >> 8;

  const float si_r = si_g[(size_t)(b * N + i0 + ci) * H + ch];
  const float m_r = m_g[(size_t)(b * N + i0 + ci) * H + ch];

  const float* hb = h_g + (size_t)b * N * OUTD;
  const int* adjb = adj + ((size_t)b * N + i0) * N;
  const float* sjb = sj_g + (size_t)b * N * H;

  float acc[16] = {};

  for (int jt = 0; jt < 32; ++jt) {
    const int j0 = jt * 32;
    __syncthreads();
    // stage h tile: 32 rows x 256 -> 2048 float4, 4 per thread
#pragma unroll
    for (int k = 0; k < 4; ++k) {
      const int f = t + k * 512;
      const int row = f >> 6, c4 = (f & 63) << 2;
      *(float4*)&h_lds[row][c4] = *(const float4*)(hb + (size_t)(j0 + row) * OUTD + c4);
    }
    if (t < 256) {  // adj tile: 32x32 ints
      const int r = t >> 3, c4 = (t & 7) << 2;
      int4 av = *(const int4*)(adjb + (size_t)r * N + j0 + c4);
      adj_lds[r][c4 + 0] = av.x; adj_lds[r][c4 + 1] = av.y;
      adj_lds[r][c4 + 2] = av.z; adj_lds[r][c4 + 3] = av.w;
    } else {        // s_j tile: 32x8
      const int tt = t - 256;
      sj_lds[tt >> 3][tt & 7] = sjb[(size_t)(j0 + (tt >> 3)) * H + (tt & 7)];
    }
    __syncthreads();
    // compute w
#pragma unroll
    for (int jj = 0; jj < 16; ++jj) {
      const int j = cjh * 16 + jj;
      float e = si_r + sj_lds[j][ch];
      e = e > 0.f ? e : 0.2f * e;
      if (adj_lds[ci][j] == 0) e = NEG;
      w_lds[j][ch][ci] = __expf(e - m_r);
    }
    __syncthreads();
    // FMA: acc[i] += w[j][h][i] * h[j][h*32+d]
#pragma unroll
    for (int j = 0; j < 32; ++j) {
      const float hv = h_lds[j][fh * 32 + fd];
      const float4* wrow = (const float4*)&w_lds[j][fh][fih * 16];
#pragma unroll
      for (int q = 0; q < 4; ++q) {
        float4 w4 = wrow[q];
        acc[q * 4 + 0] += w4.x * hv;
        acc[q * 4 + 1] += w4.y * hv;
        acc[q * 4 + 2] += w4.z * hv;
        acc[q * 4 + 3] += w4.w * hv;
      }
    }
  }
  // epilogue: /l, ELU, store
#pragma unroll
  for (int q = 0; q < 16; ++q) {
    const int i = fih * 16 + q;
    const float l = l_g[(size_t)(b * N + i0 + i) * H + fh];
    float v = acc[q] / l;
    v = v > 0.f ? v : expm1f(v);
    out[(size_t)(b * N + i0 + i) * OUTD + fh * 32 + fd] = v;
  }
}

extern "C" void kernel_launch(void* const* d_in, const int* in_sizes, int n_in,
                              void* d_out, int out_size, void* d_ws, size_t ws_size,
                              hipStream_t stream) {
  const float* x = (const float*)d_in[0];
  const int* adj = (const int*)d_in[1];
  const float* W = (const float*)d_in[2];
  const float* a = (const float*)d_in[3];
  float* out = (float*)d_out;

  float* ws = (float*)d_ws;
  float* h = ws;                              // B*N*OUTD = 2097152
  float* si = h + (size_t)B * N * OUTD;       // B*N*H = 65536
  float* sj = si + (size_t)B * N * H;
  float* m = sj + (size_t)B * N * H;
  float* l = m + (size_t)B * N * H;

  dim3 g1(B * N / 64, OUTD / 64);
  gat_gemm<<<g1, 256, 0, stream>>>(x, W, h);
  gat_scores<<<B * N, 256, 0, stream>>>(h, a, si, sj);
  gat_stats<<<B * N, 256, 0, stream>>>(adj, si, sj, m, l);
  gat_agg<<<B * (N / 32), 512, 0, stream>>>(adj, h, si, m, sj, l, out);
}

// Round 2
// 105.552 us; speedup vs baseline: 2.0141x; 2.0141x over previous
//
#include <hip/hip_runtime.h>
#include <cmath>

namespace {
constexpr int B = 8, N = 1024, IND = 256, OUTD = 256, H = 8, D = 32;
}

typedef __attribute__((ext_vector_type(8))) short short8v;
typedef __attribute__((ext_vector_type(4))) float f32x4;

__device__ inline ushort f2bf(float f) {
  __bf16 b = (__bf16)f;
  return __builtin_bit_cast(ushort, b);
}

// ---------------------------------------------------------------------------
// K1: h[b,n,o] = sum_i x[b,n,i] * W[o,i]   (fp32, unchanged from round 1)
// ---------------------------------------------------------------------------
__global__ __launch_bounds__(256) void gat_gemm(const float* __restrict__ x,
                                                const float* __restrict__ W,
                                                float* __restrict__ hout) {
  __shared__ float xs[64][17];
  __shared__ float ws[64][17];
  const int t = threadIdx.x;
  const int bm = blockIdx.x, bn = blockIdx.y;
  const int srow = t >> 2, sc = (t & 3) << 2;
  const int tx = t & 15, ty = t >> 4;
  const float* xp = x + (size_t)(bm * 64) * IND;
  const float* wp = W + (size_t)(bn * 64) * IND;
  float acc[4][4] = {};
  for (int ks = 0; ks < IND; ks += 16) {
    __syncthreads();
    float4 xv = *(const float4*)(xp + srow * IND + ks + sc);
    float4 wv = *(const float4*)(wp + srow * IND + ks + sc);
    xs[srow][sc + 0] = xv.x; xs[srow][sc + 1] = xv.y;
    xs[srow][sc + 2] = xv.z; xs[srow][sc + 3] = xv.w;
    ws[srow][sc + 0] = wv.x; ws[srow][sc + 1] = wv.y;
    ws[srow][sc + 2] = wv.z; ws[srow][sc + 3] = wv.w;
    __syncthreads();
#pragma unroll
    for (int kk = 0; kk < 16; ++kk) {
      float av[4], bv[4];
#pragma unroll
      for (int r = 0; r < 4; ++r) av[r] = xs[ty * 4 + r][kk];
#pragma unroll
      for (int c = 0; c < 4; ++c) bv[c] = ws[tx * 4 + c][kk];
#pragma unroll
      for (int r = 0; r < 4; ++r)
#pragma unroll
        for (int c = 0; c < 4; ++c) acc[r][c] += av[r] * bv[c];
    }
  }
#pragma unroll
  for (int r = 0; r < 4; ++r) {
    float4 v = make_float4(acc[r][0], acc[r][1], acc[r][2], acc[r][3]);
    *(float4*)(hout + (size_t)(bm * 64 + ty * 4 + r) * OUTD + bn * 64 + tx * 4) = v;
  }
}

// ---------------------------------------------------------------------------
// K2: bit-pack adjacency. One wave reads 64 consecutive adj ints; __ballot
// produces the 64-bit mask directly.
// ---------------------------------------------------------------------------
__global__ __launch_bounds__(256) void gat_bitpack(const int* __restrict__ adj,
                                                   unsigned long long* __restrict__ bits) {
  const size_t idx = (size_t)blockIdx.x * 256 + threadIdx.x;
  const unsigned long long m = __ballot(adj[idx] != 0);
  if ((threadIdx.x & 63) == 0) bits[idx >> 6] = m;
}

// ---------------------------------------------------------------------------
// K3: per (b,h,j-tile of 128): stage h slice, compute s_i/s_j scores
// (transposed layout [b][h][n]) and write hTb[b][h][d][j] in bf16.
// ---------------------------------------------------------------------------
__global__ __launch_bounds__(256) void gat_trans(const float* __restrict__ h,
                                                 const float* __restrict__ a,
                                                 float* __restrict__ siT,
                                                 float* __restrict__ sjT,
                                                 ushort* __restrict__ hTb) {
  __shared__ float tile[128][33];
  const int t = threadIdx.x;
  const int bh = blockIdx.x;  // b*8 + h
  const int b = bh >> 3, hh = bh & 7;
  const int j0 = blockIdx.y * 128;
  const float* hp = h + ((size_t)b * N + j0) * OUTD + hh * D;
#pragma unroll
  for (int k = 0; k < 4; ++k) {
    const int f = t + k * 256;
    const int row = f >> 3, c4 = (f & 7) * 4;
    float4 v = *(const float4*)(hp + (size_t)row * OUTD + c4);
    tile[row][c4] = v.x; tile[row][c4 + 1] = v.y;
    tile[row][c4 + 2] = v.z; tile[row][c4 + 3] = v.w;
  }
  __syncthreads();
  // scores: 2 threads per j-row, each sums 16 d
  {
    const int row = t >> 1, half = t & 1;
    float s1 = 0.f, s2 = 0.f;
#pragma unroll
    for (int q = 0; q < 16; ++q) {
      const int d = half * 16 + q;
      const float hv = tile[row][d];
      s1 += hv * a[hh * 64 + d];
      s2 += hv * a[hh * 64 + 32 + d];
    }
    s1 += __shfl_xor(s1, 1);
    s2 += __shfl_xor(s2, 1);
    if (half == 0) {
      siT[(size_t)bh * N + j0 + row] = s1;
      sjT[(size_t)bh * N + j0 + row] = s2;
    }
  }
  // transposed bf16 store: thread = (d, octet of 16 j)
  {
    const int d = t >> 3, oct = t & 7;
#pragma unroll
    for (int q = 0; q < 2; ++q) {
      const int jj = oct * 16 + q * 8;
      short8v pk;
#pragma unroll
      for (int e = 0; e < 8; ++e) pk[e] = (short)f2bf(tile[jj + e][d]);
      *(short8v*)(hTb + ((size_t)bh * D + d) * N + j0 + jj) = pk;
    }
  }
}

// ---------------------------------------------------------------------------
// K4: MFMA aggregation. Block = 256 thr = 4 waves; wave owns 16 i-rows of a
// 64-row i-tile for one (b,h). No LDS, no barriers. A-frag (exp weights)
// built in registers in MFMA layout; B-frags are 16B global loads from hTb.
// l (softmax denom) accumulated from the bf16-rounded weights; no max
// subtraction needed (e bounded, masked -> exactly 0).
// ---------------------------------------------------------------------------
__global__ __launch_bounds__(256) void gat_agg_mfma(
    const uint* __restrict__ bits32, const float* __restrict__ siT,
    const float* __restrict__ sjT, const ushort* __restrict__ hTb,
    float* __restrict__ out) {
  const int t = threadIdx.x;
  const int lane = t & 63, w = t >> 6;
  const int bh = blockIdx.x >> 4;  // b*8+h
  const int it = blockIdx.x & 15;
  const int b = bh >> 3, hh = bh & 7;
  const int i0 = it * 64 + w * 16;
  const int la = lane & 15, g = lane >> 4;

  const int iA = i0 + la;  // this lane's A-row (and score row)
  const float si_r = siT[(size_t)bh * N + iA];
  const uint* bp = bits32 + ((size_t)(b * N) + iA) * (N / 32);
  const float* sjp = sjT + (size_t)bh * N + g * 8;
  const ushort* hb0 = hTb + ((size_t)bh * D + la) * N + g * 8;
  const ushort* hb1 = hTb + ((size_t)bh * D + 16 + la) * N + g * 8;

  f32x4 acc0 = {0.f, 0.f, 0.f, 0.f}, acc1 = {0.f, 0.f, 0.f, 0.f};
  float accl = 0.f;

  uint bits_c = bp[0];
  float4 sjA = *(const float4*)(sjp);
  float4 sjB = *(const float4*)(sjp + 4);
  short8v b0c = *(const short8v*)(hb0);
  short8v b1c = *(const short8v*)(hb1);

  for (int jt = 0; jt < 32; ++jt) {
    const int jn = jt < 31 ? jt + 1 : 31;  // clamped prefetch (last iter harmless)
    const uint bits_n = bp[jn];
    const float4 sjA_n = *(const float4*)(sjp + jn * 32);
    const float4 sjB_n = *(const float4*)(sjp + jn * 32 + 4);
    const short8v b0n = *(const short8v*)(hb0 + jn * 32);
    const short8v b1n = *(const short8v*)(hb1 + jn * 32);

    const uint byte = (bits_c >> (g * 8)) & 0xffu;
    const float sjv[8] = {sjA.x, sjA.y, sjA.z, sjA.w, sjB.x, sjB.y, sjB.z, sjB.w};
    short8v af;
#pragma unroll
    for (int e = 0; e < 8; ++e) {
      float ev = si_r + sjv[e];
      ev = ev > 0.f ? ev : 0.2f * ev;  // leaky relu
      float wv = __expf(ev);
      wv = ((byte >> e) & 1u) ? wv : 0.f;  // mask -> exact 0
      const ushort wb = f2bf(wv);
      af[e] = (short)wb;
      accl += __uint_as_float((uint)wb << 16);  // sum the bf16-rounded weight
    }
    acc0 = __builtin_amdgcn_mfma_f32_16x16x32_bf16(af, b0c, acc0, 0, 0, 0);
    acc1 = __builtin_amdgcn_mfma_f32_16x16x32_bf16(af, b1c, acc1, 0, 0, 0);

    bits_c = bits_n; sjA = sjA_n; sjB = sjB_n; b0c = b0n; b1c = b1n;
  }
  // denominator: combine the 4 j-octet groups for each A-row
  accl += __shfl_xor(accl, 16);
  accl += __shfl_xor(accl, 32);

  float* op = out + ((size_t)(b * N + i0)) * OUTD + hh * D;
#pragma unroll
  for (int r = 0; r < 4; ++r) {
    const int ic = g * 4 + r;               // C row (m89-verified layout)
    const float li = __shfl(accl, ic);      // lane ic holds l for row ic
    float v0 = acc0[r] / li;
    v0 = v0 > 0.f ? v0 : expm1f(v0);
    op[(size_t)ic * OUTD + la] = v0;
    float v1 = acc1[r] / li;
    v1 = v1 > 0.f ? v1 : expm1f(v1);
    op[(size_t)ic * OUTD + 16 + la] = v1;
  }
}

extern "C" void kernel_launch(void* const* d_in, const int* in_sizes, int n_in,
                              void* d_out, int out_size, void* d_ws, size_t ws_size,
                              hipStream_t stream) {
  const float* x = (const float*)d_in[0];
  const int* adj = (const int*)d_in[1];
  const float* W = (const float*)d_in[2];
  const float* a = (const float*)d_in[3];
  float* out = (float*)d_out;

  float* ws = (float*)d_ws;
  float* h = ws;                                   // 2,097,152 f32 (8 MB)
  float* siT = h + (size_t)B * N * OUTD;           // 65,536 f32
  float* sjT = siT + (size_t)B * N * H;            // 65,536 f32
  uint* bits = (uint*)(sjT + (size_t)B * N * H);   // 262,144 u32 (1 MB)
  ushort* hTb = (ushort*)(bits + (size_t)B * N * N / 32);  // 2,097,152 bf16 (4 MB)

  gat_gemm<<<dim3(B * N / 64, OUTD / 64), 256, 0, stream>>>(x, W, h);
  gat_bitpack<<<B * N * N / 256, 256, 0, stream>>>(adj, (unsigned long long*)bits);
  gat_trans<<<dim3(B * H, N / 128), 256, 0, stream>>>(h, a, siT, sjT, hTb);
  gat_agg_mfma<<<B * H * (N / 64), 256, 0, stream>>>(bits, siT, sjT, hTb, out);
}

// Round 3
// 93.378 us; speedup vs baseline: 2.2766x; 1.1304x over previous
//
#include <hip/hip_runtime.h>
#include <cmath>

namespace {
constexpr int B = 8, N = 1024, IND = 256, OUTD = 256, H = 8, D = 32;
constexpr float LOG2E = 1.4426950408889634f;
}

typedef __attribute__((ext_vector_type(8))) short short8v;
typedef __attribute__((ext_vector_type(4))) float f32x4;

__device__ inline ushort f2bf(float f) {
  __bf16 b = (__bf16)f;
  return __builtin_bit_cast(ushort, b);
}
__device__ inline float bf2f(ushort u) {
  return __uint_as_float((uint)u << 16);
}

// ---------------------------------------------------------------------------
// K0: prep. Wfrag_h/Wfrag_l = split-bf16 of W, pre-swizzled into the exact
// MFMA B-fragment layout: Wfrag[((kb*16+ct)*64+l)*8+e] = bf16(W[c][k]),
// c = ct*16+(l&15), k = kb*32+(l>>4)*8+e.  Also a_s = a * log2(e).
// ---------------------------------------------------------------------------
__global__ __launch_bounds__(256) void gat_prep(const float* __restrict__ W,
                                                const float* __restrict__ a,
                                                ushort* __restrict__ Wfh,
                                                ushort* __restrict__ Wfl,
                                                float* __restrict__ a_s) {
  const int idx = blockIdx.x * 256 + threadIdx.x;  // 0..131071
  const int e = idx & 7, l = (idx >> 3) & 63, ct = (idx >> 9) & 15, kb = idx >> 13;
  const int c = ct * 16 + (l & 15);
  const int k = kb * 32 + (l >> 4) * 8 + e;
  const float v = W[c * IND + k];
  const ushort hi = f2bf(v);
  Wfh[idx] = hi;
  Wfl[idx] = f2bf(v - bf2f(hi));
  if (idx < 512) a_s[idx] = a[idx] * LOG2E;
}

// ---------------------------------------------------------------------------
// K1: fused GEMM (split-bf16 MFMA, fp32-accurate) + scores + transposed bf16
// store. Block = 256 thr (4 waves); wave owns 32 rows x 32 cols (one head).
// grid = (8192/128, H). Epilogue: C tile -> LDS -> {siT, sjT (x log2e), hTb}.
// ---------------------------------------------------------------------------
__global__ __launch_bounds__(256) void gat_gemm_fused(
    const float* __restrict__ x, const ushort* __restrict__ Wfh,
    const ushort* __restrict__ Wfl, const float* __restrict__ a_s,
    float* __restrict__ siT, float* __restrict__ sjT,
    ushort* __restrict__ hTb) {
  __shared__ float tile[128][33];
  const int t = threadIdx.x;
  const int lane = t & 63, w = t >> 6;
  const int la = lane & 15, g = lane >> 4;
  const int bx = blockIdx.x;   // 128-row tile
  const int hh = blockIdx.y;   // head (32-col group)

  f32x4 z = {0.f, 0.f, 0.f, 0.f};
  f32x4 acc00 = z, acc01 = z, acc10 = z, acc11 = z;

  const float* xp = x + (size_t)(bx * 128 + w * 32 + la) * IND + g * 8;
  const ushort* wp = Wfh + ((size_t)(hh * 2) * 64 + lane) * 8;
  const ushort* wpl = Wfl + ((size_t)(hh * 2) * 64 + lane) * 8;

#pragma unroll
  for (int kb = 0; kb < 8; ++kb) {
    float4 u0 = *(const float4*)(xp + kb * 32);
    float4 u1 = *(const float4*)(xp + kb * 32 + 4);
    float4 v0 = *(const float4*)(xp + 16 * IND + kb * 32);
    float4 v1 = *(const float4*)(xp + 16 * IND + kb * 32 + 4);
    const float af0[8] = {u0.x, u0.y, u0.z, u0.w, u1.x, u1.y, u1.z, u1.w};
    const float af1[8] = {v0.x, v0.y, v0.z, v0.w, v1.x, v1.y, v1.z, v1.w};
    short8v a0h, a0l, a1h, a1l;
#pragma unroll
    for (int e = 0; e < 8; ++e) {
      ushort h0 = f2bf(af0[e]);
      a0h[e] = (short)h0;
      a0l[e] = (short)f2bf(af0[e] - bf2f(h0));
      ushort h1 = f2bf(af1[e]);
      a1h[e] = (short)h1;
      a1l[e] = (short)f2bf(af1[e] - bf2f(h1));
    }
    short8v bh0 = *(const short8v*)(wp + kb * 8192);
    short8v bh1 = *(const short8v*)(wp + kb * 8192 + 512);
    short8v bl0 = *(const short8v*)(wpl + kb * 8192);
    short8v bl1 = *(const short8v*)(wpl + kb * 8192 + 512);

    acc00 = __builtin_amdgcn_mfma_f32_16x16x32_bf16(a0h, bh0, acc00, 0, 0, 0);
    acc01 = __builtin_amdgcn_mfma_f32_16x16x32_bf16(a0h, bh1, acc01, 0, 0, 0);
    acc10 = __builtin_amdgcn_mfma_f32_16x16x32_bf16(a1h, bh0, acc10, 0, 0, 0);
    acc11 = __builtin_amdgcn_mfma_f32_16x16x32_bf16(a1h, bh1, acc11, 0, 0, 0);
    acc00 = __builtin_amdgcn_mfma_f32_16x16x32_bf16(a0l, bh0, acc00, 0, 0, 0);
    acc01 = __builtin_amdgcn_mfma_f32_16x16x32_bf16(a0l, bh1, acc01, 0, 0, 0);
    acc10 = __builtin_amdgcn_mfma_f32_16x16x32_bf16(a1l, bh0, acc10, 0, 0, 0);
    acc11 = __builtin_amdgcn_mfma_f32_16x16x32_bf16(a1l, bh1, acc11, 0, 0, 0);
    acc00 = __builtin_amdgcn_mfma_f32_16x16x32_bf16(a0h, bl0, acc00, 0, 0, 0);
    acc01 = __builtin_amdgcn_mfma_f32_16x16x32_bf16(a0h, bl1, acc01, 0, 0, 0);
    acc10 = __builtin_amdgcn_mfma_f32_16x16x32_bf16(a1h, bl0, acc10, 0, 0, 0);
    acc11 = __builtin_amdgcn_mfma_f32_16x16x32_bf16(a1h, bl1, acc11, 0, 0, 0);
  }

  // C -> LDS (C layout: col = lane&15, row = (lane>>4)*4 + q)
#pragma unroll
  for (int q = 0; q < 4; ++q) {
    tile[w * 32 + g * 4 + q][la] = acc00[q];
    tile[w * 32 + g * 4 + q][16 + la] = acc01[q];
    tile[w * 32 + 16 + g * 4 + q][la] = acc10[q];
    tile[w * 32 + 16 + g * 4 + q][16 + la] = acc11[q];
  }
  __syncthreads();

  // scores (scaled by log2e via a_s): 2 threads per row
  {
    const int row = t >> 1, half = t & 1;
    const float* ap = a_s + hh * 64 + half * 16;
    float s1 = 0.f, s2 = 0.f;
#pragma unroll
    for (int q = 0; q < 16; ++q) {
      const float hv = tile[row][half * 16 + q];
      s1 += hv * ap[q];
      s2 += hv * ap[32 + q];
    }
    s1 += __shfl_xor(s1, 1);
    s2 += __shfl_xor(s2, 1);
    if (half == 0) {
      const int ng = bx * 128 + row;
      const int b = ng >> 10, n = ng & 1023;
      const size_t o = (size_t)(b * H + hh) * N + n;
      siT[o] = s1;
      sjT[o] = s2;
    }
  }

  // transposed bf16 store: hTb[bh][d][j]
  {
    const int b = (bx * 128) >> 10, j0 = (bx * 128) & 1023;
    const int bh = b * H + hh;
#pragma unroll
    for (int it2 = 0; it2 < 2; ++it2) {
      const int slot = t + it2 * 256;  // 0..511
      const int d = slot >> 4, oct = slot & 15;
      short8v pk;
#pragma unroll
      for (int e = 0; e < 8; ++e) pk[e] = (short)f2bf(tile[oct * 8 + e][d]);
      *(short8v*)(hTb + ((size_t)bh * D + d) * N + j0 + oct * 8) = pk;
    }
  }
}

// ---------------------------------------------------------------------------
// K2: bit-pack adjacency (64 ints -> one 64-bit mask via ballot).
// ---------------------------------------------------------------------------
__global__ __launch_bounds__(256) void gat_bitpack(const int* __restrict__ adj,
                                                   unsigned long long* __restrict__ bits) {
  const size_t idx = (size_t)blockIdx.x * 256 + threadIdx.x;
  const unsigned long long m = __ballot(adj[idx] != 0);
  if ((threadIdx.x & 63) == 0) bits[idx >> 6] = m;
}

// ---------------------------------------------------------------------------
// K3: MFMA aggregation. Block = 128 thr (2 waves); wave owns 16 i-rows;
// grid = B*H*(N/32) = 2048. A-frag (exp2 weights) built in registers; no LDS.
// ---------------------------------------------------------------------------
__global__ __launch_bounds__(128) void gat_agg_mfma(
    const uint* __restrict__ bits32, const float* __restrict__ siT,
    const float* __restrict__ sjT, const ushort* __restrict__ hTb,
    float* __restrict__ out) {
  const int t = threadIdx.x;
  const int lane = t & 63, w = t >> 6;
  const int bh = blockIdx.x >> 5;
  const int it = blockIdx.x & 31;
  const int b = bh >> 3, hh = bh & 7;
  const int i0 = it * 32 + w * 16;
  const int la = lane & 15, g = lane >> 4;

  const int iA = i0 + la;
  const float si_r = siT[(size_t)bh * N + iA];
  const uint* bp = bits32 + ((size_t)(b * N) + iA) * (N / 32);
  const float* sjp = sjT + (size_t)bh * N + g * 8;
  const ushort* hb0 = hTb + ((size_t)bh * D + la) * N + g * 8;
  const ushort* hb1 = hTb + ((size_t)bh * D + 16 + la) * N + g * 8;

  f32x4 acc0 = {0.f, 0.f, 0.f, 0.f}, acc1 = {0.f, 0.f, 0.f, 0.f};
  float accl0 = 0.f, accl1 = 0.f;

  uint bits_c = bp[0];
  float4 sjA = *(const float4*)(sjp);
  float4 sjB = *(const float4*)(sjp + 4);
  short8v b0c = *(const short8v*)(hb0);
  short8v b1c = *(const short8v*)(hb1);

  for (int jt = 0; jt < 32; ++jt) {
    const int jn = (jt + 1) & 31;  // wrap prefetch (harmless re-read of jt=0)
    const uint bits_n = bp[jn];
    const float4 sjA_n = *(const float4*)(sjp + jn * 32);
    const float4 sjB_n = *(const float4*)(sjp + jn * 32 + 4);
    const short8v b0n = *(const short8v*)(hb0 + jn * 32);
    const short8v b1n = *(const short8v*)(hb1 + jn * 32);

    const uint byte_ = (bits_c >> (g * 8)) & 0xffu;
    const float sjv[8] = {sjA.x, sjA.y, sjA.z, sjA.w, sjB.x, sjB.y, sjB.z, sjB.w};
    short8v af;
#pragma unroll
    for (int e = 0; e < 8; ++e) {
      float s = si_r + sjv[e];             // already scaled by log2e
      s = fmaxf(s, 0.2f * s);              // leaky (homogeneous under scaling)
      float wv = __builtin_amdgcn_exp2f(s);
      wv = ((byte_ >> e) & 1u) ? wv : 0.f; // mask -> exact 0
      af[e] = (short)f2bf(wv);
      if (e < 4) accl0 += wv; else accl1 += wv;
    }
    acc0 = __builtin_amdgcn_mfma_f32_16x16x32_bf16(af, b0c, acc0, 0, 0, 0);
    acc1 = __builtin_amdgcn_mfma_f32_16x16x32_bf16(af, b1c, acc1, 0, 0, 0);

    bits_c = bits_n; sjA = sjA_n; sjB = sjB_n; b0c = b0n; b1c = b1n;
  }
  float accl = accl0 + accl1;
  accl += __shfl_xor(accl, 16);
  accl += __shfl_xor(accl, 32);

  float* op = out + ((size_t)(b * N + i0)) * OUTD + hh * D;
#pragma unroll
  for (int r = 0; r < 4; ++r) {
    const int ic = g * 4 + r;
    const float li = __shfl(accl, ic);
    float v0 = acc0[r] / li;
    v0 = v0 > 0.f ? v0 : expm1f(v0);
    op[(size_t)ic * OUTD + la] = v0;
    float v1 = acc1[r] / li;
    v1 = v1 > 0.f ? v1 : expm1f(v1);
    op[(size_t)ic * OUTD + 16 + la] = v1;
  }
}

extern "C" void kernel_launch(void* const* d_in, const int* in_sizes, int n_in,
                              void* d_out, int out_size, void* d_ws, size_t ws_size,
                              hipStream_t stream) {
  const float* x = (const float*)d_in[0];
  const int* adj = (const int*)d_in[1];
  const float* W = (const float*)d_in[2];
  const float* a = (const float*)d_in[3];
  float* out = (float*)d_out;

  float* ws = (float*)d_ws;
  float* siT = ws;                                  // 65536 f32
  float* sjT = siT + (size_t)B * N * H;             // 65536 f32
  uint* bits = (uint*)(sjT + (size_t)B * N * H);    // 262144 u32
  ushort* hTb = (ushort*)(bits + (size_t)B * N * N / 32);  // 2M bf16
  ushort* Wfh = hTb + (size_t)B * N * OUTD;         // 131072 bf16
  ushort* Wfl = Wfh + 131072;                       // 131072 bf16
  float* a_s = (float*)(Wfl + 131072);              // 512 f32

  gat_prep<<<512, 256, 0, stream>>>(W, a, Wfh, Wfl, a_s);
  gat_gemm_fused<<<dim3(B * N / 128, H), 256, 0, stream>>>(x, Wfh, Wfl, a_s,
                                                           siT, sjT, hTb);
  gat_bitpack<<<B * N * N / 256, 256, 0, stream>>>(adj, (unsigned long long*)bits);
  gat_agg_mfma<<<B * H * (N / 32), 128, 0, stream>>>(bits, siT, sjT, hTb, out);
}

// Round 4
// 83.189 us; speedup vs baseline: 2.5555x; 1.1225x over previous
//
#include <hip/hip_runtime.h>
#include <cmath>

namespace {
constexpr int B = 8, N = 1024, IND = 256, OUTD = 256, H = 8, D = 32;
constexpr float LOG2E = 1.4426950408889634f;
}

typedef __attribute__((ext_vector_type(8))) short short8v;
typedef __attribute__((ext_vector_type(4))) float f32x4;

__device__ inline ushort f2bf(float f) {
  __bf16 b = (__bf16)f;
  return __builtin_bit_cast(ushort, b);
}
__device__ inline float bf2f(ushort u) {
  return __uint_as_float((uint)u << 16);
}

// ---------------------------------------------------------------------------
// K0: prep. Split-bf16 W pre-swizzled into MFMA B-fragment layout:
// Wf[((kb*16+ct)*64+l)*8+e] = bf16(W[c][k]), c=ct*16+(l&15), k=kb*32+(l>>4)*8+e.
// a_s = a * log2(e).
// ---------------------------------------------------------------------------
__global__ __launch_bounds__(256) void gat_prep(const float* __restrict__ W,
                                                const float* __restrict__ a,
                                                ushort* __restrict__ Wfh,
                                                ushort* __restrict__ Wfl,
                                                float* __restrict__ a_s) {
  const int idx = blockIdx.x * 256 + threadIdx.x;  // 0..131071
  const int e = idx & 7, l = (idx >> 3) & 63, ct = (idx >> 9) & 15, kb = idx >> 13;
  const int c = ct * 16 + (l & 15);
  const int k = kb * 32 + (l >> 4) * 8 + e;
  const float v = W[c * IND + k];
  const ushort hi = f2bf(v);
  Wfh[idx] = hi;
  Wfl[idx] = f2bf(v - bf2f(hi));
  if (idx < 512) a_s[idx] = a[idx] * LOG2E;
}

// ---------------------------------------------------------------------------
// K1: fused GEMM (split-bf16 MFMA, fp32-accurate) + in-register scores +
// transposed bf16 hTb store. Block = 256 thr (4 waves) = 64 rows x 1 head;
// wave = 16 rows x 32 cols. grid = (8192/64, H) = (128, 8).
// ---------------------------------------------------------------------------
__global__ __launch_bounds__(256) void gat_gemm_fused(
    const float* __restrict__ x, const ushort* __restrict__ Wfh,
    const ushort* __restrict__ Wfl, const float* __restrict__ a_s,
    float* __restrict__ siT, float* __restrict__ sjT,
    ushort* __restrict__ hTb) {
  __shared__ float tile[64][35];  // [row][d], pitch 35 -> <=2-way banks
  const int t = threadIdx.x;
  const int lane = t & 63, w = t >> 6;
  const int la = lane & 15, g = lane >> 4;
  const int bx = blockIdx.x;    // 64-row tile
  const int head = blockIdx.y;

  f32x4 acc0 = {0.f, 0.f, 0.f, 0.f}, acc1 = {0.f, 0.f, 0.f, 0.f};

  const float* xp = x + (size_t)(bx * 64 + w * 16 + la) * IND + g * 8;
  const ushort* wph = Wfh + ((size_t)(head * 2) * 64 + lane) * 8;
  const ushort* wpl = Wfl + ((size_t)(head * 2) * 64 + lane) * 8;

#pragma unroll
  for (int kb = 0; kb < 8; ++kb) {
    float4 u0 = *(const float4*)(xp + kb * 32);
    float4 u1 = *(const float4*)(xp + kb * 32 + 4);
    const float af[8] = {u0.x, u0.y, u0.z, u0.w, u1.x, u1.y, u1.z, u1.w};
    short8v ah, al;
#pragma unroll
    for (int e = 0; e < 8; ++e) {
      ushort hb = f2bf(af[e]);
      ah[e] = (short)hb;
      al[e] = (short)f2bf(af[e] - bf2f(hb));
    }
    short8v bh0 = *(const short8v*)(wph + kb * 8192);
    short8v bh1 = *(const short8v*)(wph + kb * 8192 + 512);
    short8v bl0 = *(const short8v*)(wpl + kb * 8192);
    short8v bl1 = *(const short8v*)(wpl + kb * 8192 + 512);

    acc0 = __builtin_amdgcn_mfma_f32_16x16x32_bf16(ah, bh0, acc0, 0, 0, 0);
    acc1 = __builtin_amdgcn_mfma_f32_16x16x32_bf16(ah, bh1, acc1, 0, 0, 0);
    acc0 = __builtin_amdgcn_mfma_f32_16x16x32_bf16(al, bh0, acc0, 0, 0, 0);
    acc1 = __builtin_amdgcn_mfma_f32_16x16x32_bf16(al, bh1, acc1, 0, 0, 0);
    acc0 = __builtin_amdgcn_mfma_f32_16x16x32_bf16(ah, bl0, acc0, 0, 0, 0);
    acc1 = __builtin_amdgcn_mfma_f32_16x16x32_bf16(ah, bl1, acc1, 0, 0, 0);
  }

  const int bglob = bx >> 4;                 // batch
  const int nbase = (bx & 15) * 64 + w * 16; // row base within batch

  // in-register scores: s[row] = sum_d C[row][d] * a_s[head*64 + d]
  {
    const float a0 = a_s[head * 64 + la];
    const float a1 = a_s[head * 64 + 16 + la];
    const float a2 = a_s[head * 64 + 32 + la];
    const float a3 = a_s[head * 64 + 48 + la];
    float s1v[4], s2v[4];
#pragma unroll
    for (int q = 0; q < 4; ++q) {
      s1v[q] = acc0[q] * a0 + acc1[q] * a1;
      s2v[q] = acc0[q] * a2 + acc1[q] * a3;
    }
#pragma unroll
    for (int mask = 1; mask <= 8; mask <<= 1)
#pragma unroll
      for (int q = 0; q < 4; ++q) {
        s1v[q] += __shfl_xor(s1v[q], mask);
        s2v[q] += __shfl_xor(s2v[q], mask);
      }
    if (la == 0) {
#pragma unroll
      for (int q = 0; q < 4; ++q) {
        const size_t o = (size_t)(bglob * H + head) * N + nbase + g * 4 + q;
        siT[o] = s1v[q];
        sjT[o] = s2v[q];
      }
    }
  }

  // C -> LDS (C layout: col = lane&15, row = (lane>>4)*4 + q)
#pragma unroll
  for (int q = 0; q < 4; ++q) {
    tile[w * 16 + g * 4 + q][la] = acc0[q];
    tile[w * 16 + g * 4 + q][16 + la] = acc1[q];
  }
  __syncthreads();

  // transposed bf16 store: hTb[(bglob*H+head)*D + d][j0 + j]
  {
    const int d = t >> 3, oct = t & 7;  // 32 d x 8 octets of 8 j
    const int j0 = (bx & 15) * 64;
    short8v pk;
#pragma unroll
    for (int e = 0; e < 8; ++e) pk[e] = (short)f2bf(tile[oct * 8 + e][d]);
    *(short8v*)(hTb + ((size_t)(bglob * H + head) * D + d) * N + j0 + oct * 8) = pk;
  }
}

// ---------------------------------------------------------------------------
// K2: bit-pack adjacency (64 ints -> one 64-bit mask via ballot).
// ---------------------------------------------------------------------------
__global__ __launch_bounds__(256) void gat_bitpack(const int* __restrict__ adj,
                                                   unsigned long long* __restrict__ bits) {
  const size_t idx = (size_t)blockIdx.x * 256 + threadIdx.x;
  const unsigned long long m = __ballot(adj[idx] != 0);
  if ((threadIdx.x & 63) == 0) bits[idx >> 6] = m;
}

// ---------------------------------------------------------------------------
// K3: MFMA aggregation, j-split. Block = 512 thr = 8 waves:
// wave w -> i-half (w&1), j-quarter (w>>2 ... w>>1). Each wave: 8 j-tiles of
// 32, A-frag (exp2 weights) in registers, 3 MFMAs/tile (acc0, acc1, l via
// all-ones B). Partials combined through LDS; jq==0 waves do the epilogue.
// grid = B*H*(N/32) = 2048.
// ---------------------------------------------------------------------------
__global__ __launch_bounds__(512) void gat_agg_mfma(
    const uint* __restrict__ bits32, const float* __restrict__ siT,
    const float* __restrict__ sjT, const ushort* __restrict__ hTb,
    float* __restrict__ out) {
  __shared__ float part[3][2][64][13];  // [jq-1][iw][lane][12]
  const int t = threadIdx.x;
  const int lane = t & 63, w = t >> 6;
  const int iw = w & 1, jq = w >> 1;
  const int bh = blockIdx.x >> 5;
  const int it = blockIdx.x & 31;
  const int b = bh >> 3, hh = bh & 7;
  const int i0 = it * 32 + iw * 16;
  const int la = lane & 15, g = lane >> 4;

  const int iA = i0 + la;
  const float si_r = siT[(size_t)bh * N + iA];
  const uint* bp = bits32 + ((size_t)(b * N) + iA) * (N / 32) + jq * 8;
  const float* sjp = sjT + (size_t)bh * N + jq * 256 + g * 8;
  const ushort* hb0 = hTb + ((size_t)bh * D + la) * N + jq * 256 + g * 8;
  const ushort* hb1 = hb0 + (size_t)16 * N;

  f32x4 acc0 = {0.f, 0.f, 0.f, 0.f}, acc1 = {0.f, 0.f, 0.f, 0.f};
  f32x4 accl = {0.f, 0.f, 0.f, 0.f};
  short8v ones;
#pragma unroll
  for (int e = 0; e < 8; ++e) ones[e] = (short)0x3F80;  // bf16(1.0)

  // prefetch buffers A/B (2 j-tiles in flight)
  uint bitsA = bp[0];
  float4 sjA0 = *(const float4*)(sjp);
  float4 sjA1 = *(const float4*)(sjp + 4);
  short8v bA0 = *(const short8v*)(hb0);
  short8v bA1 = *(const short8v*)(hb1);
  uint bitsB = bp[1];
  float4 sjB0 = *(const float4*)(sjp + 32);
  float4 sjB1 = *(const float4*)(sjp + 36);
  short8v bB0 = *(const short8v*)(hb0 + 32);
  short8v bB1 = *(const short8v*)(hb1 + 32);

#define AGG_COMPUTE(BITS, SJ0, SJ1, BB0, BB1)                                \
  {                                                                          \
    const uint byte_ = ((BITS) >> (g * 8)) & 0xffu;                          \
    const float sjv[8] = {(SJ0).x, (SJ0).y, (SJ0).z, (SJ0).w,                \
                          (SJ1).x, (SJ1).y, (SJ1).z, (SJ1).w};               \
    short8v af;                                                              \
    _Pragma("unroll") for (int e = 0; e < 8; ++e) {                          \
      float s = si_r + sjv[e];                                               \
      s = fmaxf(s, 0.2f * s);                                                \
      s = ((byte_ >> e) & 1u) ? s : -INFINITY;                               \
      af[e] = (short)f2bf(__builtin_amdgcn_exp2f(s));                        \
    }                                                                        \
    acc0 = __builtin_amdgcn_mfma_f32_16x16x32_bf16(af, (BB0), acc0, 0, 0, 0);\
    acc1 = __builtin_amdgcn_mfma_f32_16x16x32_bf16(af, (BB1), acc1, 0, 0, 0);\
    accl = __builtin_amdgcn_mfma_f32_16x16x32_bf16(af, ones, accl, 0, 0, 0); \
  }

#pragma unroll
  for (int jt = 0; jt < 8; jt += 2) {
    const int jn0 = jt + 2 < 8 ? jt + 2 : 7;
    const int jn1 = jt + 3 < 8 ? jt + 3 : 7;
    AGG_COMPUTE(bitsA, sjA0, sjA1, bA0, bA1);
    bitsA = bp[jn0];
    sjA0 = *(const float4*)(sjp + jn0 * 32);
    sjA1 = *(const float4*)(sjp + jn0 * 32 + 4);
    bA0 = *(const short8v*)(hb0 + jn0 * 32);
    bA1 = *(const short8v*)(hb1 + jn0 * 32);
    AGG_COMPUTE(bitsB, sjB0, sjB1, bB0, bB1);
    bitsB = bp[jn1];
    sjB0 = *(const float4*)(sjp + jn1 * 32);
    sjB1 = *(const float4*)(sjp + jn1 * 32 + 4);
    bB0 = *(const short8v*)(hb0 + jn1 * 32);
    bB1 = *(const short8v*)(hb1 + jn1 * 32);
  }
#undef AGG_COMPUTE

  // combine partials across j-quarters
  if (jq != 0) {
    float* p = part[jq - 1][iw][lane];
#pragma unroll
    for (int k = 0; k < 4; ++k) {
      p[k] = acc0[k];
      p[4 + k] = acc1[k];
      p[8 + k] = accl[k];
    }
  }
  __syncthreads();
  if (jq == 0) {
#pragma unroll
    for (int q = 0; q < 3; ++q) {
      const float* p = part[q][iw][lane];
#pragma unroll
      for (int k = 0; k < 4; ++k) {
        acc0[k] += p[k];
        acc1[k] += p[4 + k];
        accl[k] += p[8 + k];
      }
    }
    float* op = out + ((size_t)(b * N + i0)) * OUTD + hh * D;
#pragma unroll
    for (int r = 0; r < 4; ++r) {
      const int ic = g * 4 + r;
      const float li = accl[r];  // row-sum identical across cols
      float v0 = acc0[r] / li;
      v0 = v0 > 0.f ? v0 : expm1f(v0);
      op[(size_t)ic * OUTD + la] = v0;
      float v1 = acc1[r] / li;
      v1 = v1 > 0.f ? v1 : expm1f(v1);
      op[(size_t)ic * OUTD + 16 + la] = v1;
    }
  }
}

extern "C" void kernel_launch(void* const* d_in, const int* in_sizes, int n_in,
                              void* d_out, int out_size, void* d_ws, size_t ws_size,
                              hipStream_t stream) {
  const float* x = (const float*)d_in[0];
  const int* adj = (const int*)d_in[1];
  const float* W = (const float*)d_in[2];
  const float* a = (const float*)d_in[3];
  float* out = (float*)d_out;

  float* ws = (float*)d_ws;
  float* siT = ws;                                  // 65536 f32
  float* sjT = siT + (size_t)B * N * H;             // 65536 f32
  uint* bits = (uint*)(sjT + (size_t)B * N * H);    // 262144 u32
  ushort* hTb = (ushort*)(bits + (size_t)B * N * N / 32);  // 2M bf16
  ushort* Wfh = hTb + (size_t)B * N * OUTD;         // 131072 bf16
  ushort* Wfl = Wfh + 131072;                       // 131072 bf16
  float* a_s = (float*)(Wfl + 131072);              // 512 f32

  gat_prep<<<512, 256, 0, stream>>>(W, a, Wfh, Wfl, a_s);
  gat_gemm_fused<<<dim3(B * N / 64, H), 256, 0, stream>>>(x, Wfh, Wfl, a_s,
                                                          siT, sjT, hTb);
  gat_bitpack<<<B * N * N / 256, 256, 0, stream>>>(adj, (unsigned long long*)bits);
  gat_agg_mfma<<<B * H * (N / 32), 512, 0, stream>>>(bits, siT, sjT, hTb, out);
}

// Round 5
// 63.135 us; speedup vs baseline: 3.3672x; 1.3176x over previous
//
#include <hip/hip_runtime.h>
#include <cmath>

namespace {
constexpr int B = 8, N = 1024, IND = 256, OUTD = 256, H = 8, D = 32;
constexpr float LOG2E = 1.4426950408889634f;
}

typedef __attribute__((ext_vector_type(8))) short short8v;
typedef __attribute__((ext_vector_type(4))) float f32x4;

__device__ inline ushort f2bf(float f) {
  __bf16 b = (__bf16)f;
  return __builtin_bit_cast(ushort, b);
}
__device__ inline float bf2f(ushort u) {
  return __uint_as_float((uint)u << 16);
}

// ---------------------------------------------------------------------------
// K0a: W -> split-bf16, MFMA B-fragment-major:
// Wf[(kb*16+ct)*512 + l*8 + e] = bf16(W[ct*16+(l&15)][kb*32+(l>>4)*8+e]).
// a_s = a * log2(e).
// ---------------------------------------------------------------------------
__global__ __launch_bounds__(256) void gat_prep_w(const float* __restrict__ W,
                                                  const float* __restrict__ a,
                                                  ushort* __restrict__ Wfh,
                                                  ushort* __restrict__ Wfl,
                                                  float* __restrict__ a_s) {
  const int idx = blockIdx.x * 256 + threadIdx.x;  // 0..131071
  const int e = idx & 7, l = (idx >> 3) & 63, ct = (idx >> 9) & 15, kb = idx >> 13;
  const int c = ct * 16 + (l & 15);
  const int k = kb * 32 + (l >> 4) * 8 + e;
  const float v = W[c * IND + k];
  const ushort hi = f2bf(v);
  Wfh[idx] = hi;
  Wfl[idx] = f2bf(v - bf2f(hi));
  if (idx < 512) a_s[idx] = a[idx] * LOG2E;
}

// ---------------------------------------------------------------------------
// K0b: x -> split-bf16, MFMA A-fragment-major:
// xF[(rt*8+kb)*512 + l*8 + e] = bf16(x[rt*16+(l&15)][kb*32+(l>>4)*8+e]).
// Block = one 16-row tile; coalesced read via LDS; coalesced 32B writes.
// ---------------------------------------------------------------------------
__global__ __launch_bounds__(256) void gat_prep_x(const float* __restrict__ x,
                                                  ushort* __restrict__ xFh,
                                                  ushort* __restrict__ xFl) {
  __shared__ float tile[16][257];
  const int t = threadIdx.x;
  const int rt = blockIdx.x;  // 0..511
  {
    const int r = t >> 4, c0 = (t & 15) * 16;
    const float* xp = x + ((size_t)rt * 16 + r) * IND + c0;
#pragma unroll
    for (int q = 0; q < 4; ++q) {
      float4 v = *(const float4*)(xp + q * 4);
      tile[r][c0 + q * 4 + 0] = v.x;
      tile[r][c0 + q * 4 + 1] = v.y;
      tile[r][c0 + q * 4 + 2] = v.z;
      tile[r][c0 + q * 4 + 3] = v.w;
    }
  }
  __syncthreads();
#pragma unroll
  for (int s = 0; s < 2; ++s) {
    const int gi = t * 2 + s;            // 0..511
    const int l = gi & 63, kb = gi >> 6;
    const int row = l & 15;
    const int k0 = kb * 32 + (l >> 4) * 8;
    short8v ph, pl;
#pragma unroll
    for (int e = 0; e < 8; ++e) {
      const float v = tile[row][k0 + e];
      const ushort hi = f2bf(v);
      ph[e] = (short)hi;
      pl[e] = (short)f2bf(v - bf2f(hi));
    }
    *(short8v*)(xFh + ((size_t)rt * 512 + gi) * 8) = ph;
    *(short8v*)(xFl + ((size_t)rt * 512 + gi) * 8) = pl;
  }
}

// ---------------------------------------------------------------------------
// K1: GEMM (split-bf16 MFMA, 3-term compensation) + in-register scores +
// fragment-major hTbF store. Block = 256 thr = 4 waves (stacked rows);
// wave = 16 rows x 64 cols (2 heads). grid = (8192/64, 256/64) = (128, 4).
// All A/B loads are contiguous 1KB wave streams.
// ---------------------------------------------------------------------------
__global__ __launch_bounds__(256) void gat_gemm(
    const ushort* __restrict__ xFh, const ushort* __restrict__ xFl,
    const ushort* __restrict__ Wfh, const ushort* __restrict__ Wfl,
    const float* __restrict__ a_s, float* __restrict__ siT,
    float* __restrict__ sjT, ushort* __restrict__ hTbF) {
  __shared__ float tile2[64][65];
  const int t = threadIdx.x, lane = t & 63, w = t >> 6;
  const int la = lane & 15, g = lane >> 4;
  const int bx = blockIdx.x, by = blockIdx.y;
  const int rt = bx * 4 + w;  // 16-row tile id

  f32x4 z = {0.f, 0.f, 0.f, 0.f};
  f32x4 acc[4] = {z, z, z, z};

  const ushort* ap_h = xFh + (size_t)rt * 4096 + lane * 8;
  const ushort* ap_l = xFl + (size_t)rt * 4096 + lane * 8;
  const ushort* bp_h = Wfh + (size_t)(by * 4) * 512 + lane * 8;
  const ushort* bp_l = Wfl + (size_t)(by * 4) * 512 + lane * 8;

#pragma unroll
  for (int kb = 0; kb < 8; ++kb) {
    const short8v ah = *(const short8v*)(ap_h + kb * 512);
    const short8v al = *(const short8v*)(ap_l + kb * 512);
#pragma unroll
    for (int ct = 0; ct < 4; ++ct) {
      const short8v bh = *(const short8v*)(bp_h + (kb * 16 + ct) * 512);
      const short8v bl = *(const short8v*)(bp_l + (kb * 16 + ct) * 512);
      acc[ct] = __builtin_amdgcn_mfma_f32_16x16x32_bf16(ah, bh, acc[ct], 0, 0, 0);
      acc[ct] = __builtin_amdgcn_mfma_f32_16x16x32_bf16(al, bh, acc[ct], 0, 0, 0);
      acc[ct] = __builtin_amdgcn_mfma_f32_16x16x32_bf16(ah, bl, acc[ct], 0, 0, 0);
    }
  }

  const int batch = bx >> 4;            // 16 row-blocks per batch
  const int nbase = (rt & 63) * 16;     // row base within batch

  // in-register scores (a_s already has log2e folded in)
#pragma unroll
  for (int hp2 = 0; hp2 < 2; ++hp2) {
    const int head = by * 2 + hp2;
    const float a0 = a_s[head * 64 + la];
    const float a1 = a_s[head * 64 + 16 + la];
    const float a2 = a_s[head * 64 + 32 + la];
    const float a3 = a_s[head * 64 + 48 + la];
    float s1v[4], s2v[4];
#pragma unroll
    for (int q = 0; q < 4; ++q) {
      s1v[q] = acc[hp2 * 2][q] * a0 + acc[hp2 * 2 + 1][q] * a1;
      s2v[q] = acc[hp2 * 2][q] * a2 + acc[hp2 * 2 + 1][q] * a3;
    }
#pragma unroll
    for (int mask = 1; mask <= 8; mask <<= 1)
#pragma unroll
      for (int q = 0; q < 4; ++q) {
        s1v[q] += __shfl_xor(s1v[q], mask);
        s2v[q] += __shfl_xor(s2v[q], mask);
      }
    if (la == 0) {
#pragma unroll
      for (int q = 0; q < 4; ++q) {
        const size_t o = (size_t)(batch * H + head) * N + nbase + g * 4 + q;
        siT[o] = s1v[q];
        sjT[o] = s2v[q];
      }
    }
  }

  // C -> LDS (C layout: col = lane&15, row = (lane>>4)*4 + q)
#pragma unroll
  for (int ct = 0; ct < 4; ++ct)
#pragma unroll
    for (int q = 0; q < 4; ++q)
      tile2[w * 16 + g * 4 + q][ct * 16 + la] = acc[ct][q];
  __syncthreads();

  // fragment-major bf16 store:
  // hTbF[((bh*32+jt)*64 + l)*16 + half*8 + e] = h[j = jt*32+(l>>4)*8+e][d = half*16+(l&15)]
  const int jt0 = (bx & 15) * 2;
#pragma unroll
  for (int s = 0; s < 2; ++s) {
    const int gg = t * 2 + s;  // 0..511
    const int head = gg >> 8, rem = gg & 255;
    const int jt_loc = rem >> 7, half = (rem >> 6) & 1, l = rem & 63;
    const int d = half * 16 + (l & 15);
    short8v pk;
#pragma unroll
    for (int e = 0; e < 8; ++e)
      pk[e] = (short)f2bf(tile2[jt_loc * 32 + (l >> 4) * 8 + e][head * 32 + d]);
    const int bh_g = batch * H + by * 2 + head;
    *(short8v*)(hTbF + ((size_t)(bh_g * 32 + jt0 + jt_loc) * 64 + l) * 16 + half * 8) = pk;
  }
}

// ---------------------------------------------------------------------------
// K2: bit-pack adjacency into TRANSPOSED bitsT[b][jt][i] (jt = j/32):
// agg's mask load becomes a coalesced 64B line over i.
// ---------------------------------------------------------------------------
__global__ __launch_bounds__(256) void gat_bitpack(const int* __restrict__ adj,
                                                   uint* __restrict__ bitsT) {
  const size_t idx = (size_t)blockIdx.x * 256 + threadIdx.x;
  const int lane = (int)(idx & 63);
  const size_t wid = idx >> 6;
  const int jw = (int)(wid & 15);
  const int i = (int)((wid >> 4) & 1023);
  const int b = (int)(wid >> 14);
  const int v = adj[((size_t)b * N + i) * N + jw * 64 + lane];
  const unsigned long long m = __ballot(v != 0);
  if (lane == 0) {
    bitsT[((size_t)b * 32 + jw * 2) * N + i] = (uint)m;
    bitsT[((size_t)b * 32 + jw * 2 + 1) * N + i] = (uint)(m >> 32);
  }
}

// ---------------------------------------------------------------------------
// K3: MFMA aggregation. Block = 256 thr = 4 independent waves (no LDS, no
// barriers); wave = 16 i-rows x full N, 32 j-tiles, 4-deep static pipeline.
// All loads contiguous/broadcast. l via ones-MFMA. grid = 64 bh x 16 = 1024.
// ---------------------------------------------------------------------------
__global__ __launch_bounds__(256) void gat_agg(
    const uint* __restrict__ bitsT, const float* __restrict__ siT,
    const float* __restrict__ sjT, const ushort* __restrict__ hTbF,
    float* __restrict__ out) {
  const int t = threadIdx.x;
  const int lane = t & 63, w = t >> 6;
  const int bh = blockIdx.x >> 4;
  const int itg = blockIdx.x & 15;
  const int b = bh >> 3, hh = bh & 7;
  const int i0 = (itg * 4 + w) * 16;
  const int la = lane & 15, g = lane >> 4;
  const int iA = i0 + la;

  const float si_r = siT[(size_t)bh * N + iA];
  const uint* btp = bitsT + (size_t)b * 32 * N + iA;         // + jt*1024
  const float* sjp = sjT + (size_t)bh * N + g * 8;           // + jt*32
  const ushort* hp = hTbF + (size_t)bh * 32768 + lane * 16;  // + jt*1024

  f32x4 acc0 = {0.f, 0.f, 0.f, 0.f}, acc1 = {0.f, 0.f, 0.f, 0.f};
  f32x4 accl = {0.f, 0.f, 0.f, 0.f};
  short8v ones;
#pragma unroll
  for (int e = 0; e < 8; ++e) ones[e] = (short)0x3F80;  // bf16(1.0)

  uint bits0, bits1, bits2, bits3;
  float4 sjA0, sjA1, sjA2, sjA3, sjB0, sjB1, sjB2, sjB3;
  short8v b00, b01, b02, b03, b10, b11, b12, b13;

#define AGG_LOAD(S, JT)                                      \
  bits##S = btp[(size_t)(JT) * 1024];                        \
  sjA##S = *(const float4*)(sjp + (JT) * 32);                \
  sjB##S = *(const float4*)(sjp + (JT) * 32 + 4);            \
  b0##S = *(const short8v*)(hp + (size_t)(JT) * 1024);       \
  b1##S = *(const short8v*)(hp + (size_t)(JT) * 1024 + 8);

#define AGG_COMP(S)                                                           \
  {                                                                           \
    const uint byte_ = (bits##S >> (g * 8)) & 0xffu;                          \
    const float sjv[8] = {sjA##S.x, sjA##S.y, sjA##S.z, sjA##S.w,             \
                          sjB##S.x, sjB##S.y, sjB##S.z, sjB##S.w};            \
    short8v af;                                                               \
    _Pragma("unroll") for (int e = 0; e < 8; ++e) {                           \
      float s = si_r + sjv[e];                                                \
      s = fmaxf(s, 0.2f * s);                                                 \
      s = ((byte_ >> e) & 1u) ? s : -INFINITY;                                \
      af[e] = (short)f2bf(__builtin_amdgcn_exp2f(s));                         \
    }                                                                         \
    acc0 = __builtin_amdgcn_mfma_f32_16x16x32_bf16(af, b0##S, acc0, 0, 0, 0); \
    acc1 = __builtin_amdgcn_mfma_f32_16x16x32_bf16(af, b1##S, acc1, 0, 0, 0); \
    accl = __builtin_amdgcn_mfma_f32_16x16x32_bf16(af, ones, accl, 0, 0, 0);  \
  }

  AGG_LOAD(0, 0)
  AGG_LOAD(1, 1)
  AGG_LOAD(2, 2)
  AGG_LOAD(3, 3)
#pragma unroll
  for (int jt = 0; jt < 32; jt += 4) {
    AGG_COMP(0)
    if (jt + 4 < 32) { AGG_LOAD(0, jt + 4) }
    AGG_COMP(1)
    if (jt + 5 < 32) { AGG_LOAD(1, jt + 5) }
    AGG_COMP(2)
    if (jt + 6 < 32) { AGG_LOAD(2, jt + 6) }
    AGG_COMP(3)
    if (jt + 7 < 32) { AGG_LOAD(3, jt + 7) }
  }
#undef AGG_LOAD
#undef AGG_COMP

  float* op = out + ((size_t)(b * N + i0)) * OUTD + hh * D;
#pragma unroll
  for (int r = 0; r < 4; ++r) {
    const int ic = g * 4 + r;
    const float li = accl[r];  // row-sum (identical across cols)
    float v0 = acc0[r] / li;
    v0 = v0 > 0.f ? v0 : expm1f(v0);
    op[(size_t)ic * OUTD + la] = v0;
    float v1 = acc1[r] / li;
    v1 = v1 > 0.f ? v1 : expm1f(v1);
    op[(size_t)ic * OUTD + 16 + la] = v1;
  }
}

extern "C" void kernel_launch(void* const* d_in, const int* in_sizes, int n_in,
                              void* d_out, int out_size, void* d_ws, size_t ws_size,
                              hipStream_t stream) {
  const float* x = (const float*)d_in[0];
  const int* adj = (const int*)d_in[1];
  const float* W = (const float*)d_in[2];
  const float* a = (const float*)d_in[3];
  float* out = (float*)d_out;

  // xFh/xFl live in d_out (8 MB, exact fit) — consumed by gemm, then agg
  // overwrites every byte of d_out with the final output.
  ushort* xFh = (ushort*)d_out;                   // 2,097,152 bf16
  ushort* xFl = xFh + (size_t)2097152;            // 2,097,152 bf16

  float* ws = (float*)d_ws;
  float* siT = ws;                                   // 65,536 f32
  float* sjT = siT + (size_t)B * N * H;              // 65,536 f32
  uint* bitsT = (uint*)(sjT + (size_t)B * N * H);    // 262,144 u32 (1 MB)
  ushort* hTbF = (ushort*)(bitsT + (size_t)B * 32 * N);  // 2,097,152 bf16 (4 MB)
  ushort* Wfh = hTbF + (size_t)B * N * OUTD;         // 131,072 bf16
  ushort* Wfl = Wfh + 131072;                        // 131,072 bf16
  float* a_s = (float*)(Wfl + 131072);               // 512 f32

  gat_prep_w<<<512, 256, 0, stream>>>(W, a, Wfh, Wfl, a_s);
  gat_prep_x<<<512, 256, 0, stream>>>(x, xFh, xFl);
  gat_gemm<<<dim3(128, 4), 256, 0, stream>>>(xFh, xFl, Wfh, Wfl, a_s, siT, sjT, hTbF);
  gat_bitpack<<<32768, 256, 0, stream>>>(adj, bitsT);
  gat_agg<<<64 * 16, 256, 0, stream>>>(bitsT, siT, sjT, hTbF, out);
}

// Round 6
// 54.575 us; speedup vs baseline: 3.8954x; 1.1568x over previous
//
#include <hip/hip_runtime.h>
#include <cmath>

namespace {
constexpr int B = 8, N = 1024, IND = 256, OUTD = 256, H = 8, D = 32;
constexpr float LOG2E = 1.4426950408889634f;
}

typedef __attribute__((ext_vector_type(8))) short short8v;
typedef __attribute__((ext_vector_type(4))) float f32x4;

__device__ inline ushort f2bf(float f) {
  __bf16 b = (__bf16)f;
  return __builtin_bit_cast(ushort, b);
}
__device__ inline float bf2f(ushort u) {
  return __uint_as_float((uint)u << 16);
}

// ---------------------------------------------------------------------------
// K1: heterogeneous pre-pass.
//  blocks [0, 32768): bit-pack adjacency into TRANSPOSED bitsT[b][jt][i].
//  blocks [32768, 33280): W -> split-bf16 MFMA B-fragment-major + a_s.
// ---------------------------------------------------------------------------
__global__ __launch_bounds__(256) void gat_pre(const int* __restrict__ adj,
                                               const float* __restrict__ W,
                                               const float* __restrict__ a,
                                               uint* __restrict__ bitsT,
                                               ushort* __restrict__ Wfh,
                                               ushort* __restrict__ Wfl,
                                               float* __restrict__ a_s) {
  const int bid = blockIdx.x;
  const int t = threadIdx.x;
  if (bid < 32768) {
    const size_t idx = (size_t)bid * 256 + t;
    const int lane = (int)(idx & 63);
    const size_t wid = idx >> 6;
    const int jw = (int)(wid & 15);
    const int i = (int)((wid >> 4) & 1023);
    const int b = (int)(wid >> 14);
    const int v = adj[((size_t)b * N + i) * N + jw * 64 + lane];
    const unsigned long long m = __ballot(v != 0);
    if (lane == 0) {
      bitsT[((size_t)b * 32 + jw * 2) * N + i] = (uint)m;
      bitsT[((size_t)b * 32 + jw * 2 + 1) * N + i] = (uint)(m >> 32);
    }
  } else {
    const int idx = (bid - 32768) * 256 + t;  // 0..131071
    const int e = idx & 7, l = (idx >> 3) & 63, ct = (idx >> 9) & 15,
              kb = idx >> 13;
    const int c = ct * 16 + (l & 15);
    const int k = kb * 32 + (l >> 4) * 8 + e;
    const float v = W[c * IND + k];
    const ushort hi = f2bf(v);
    Wfh[idx] = hi;
    Wfl[idx] = f2bf(v - bf2f(hi));
    if (idx < 512) a_s[idx] = a[idx] * LOG2E;
  }
}

// ---------------------------------------------------------------------------
// K2: GEMM (split-bf16 MFMA, 3-term compensation), x converted in-kernel via
// LDS staging (no xF round-trip), Wf fragments LDS-deduped across the 4
// waves. Epilogue: in-register scores + fragment-major hTbF store.
// Block = 256 thr = 4 row-stacked waves = 64 rows x 64 cols.
// grid = 512 (XCD-swizzled -> bx in 0..127, by in 0..3).
// ---------------------------------------------------------------------------
__global__ __launch_bounds__(256) void gat_gemm(
    const float* __restrict__ x, const ushort* __restrict__ Wfh,
    const ushort* __restrict__ Wfl, const float* __restrict__ a_s,
    float* __restrict__ siT, float* __restrict__ sjT,
    ushort* __restrict__ hTbF) {
  __shared__ __align__(16) char smem[17664];
  float(*xs)[36] = (float(*)[36])smem;        // 64 x 36 f32 (9216 B)
  ushort* wsh = (ushort*)(smem + 9216);       // 2048 ushort (4 KB)
  ushort* wsl = (ushort*)(smem + 13312);      // 2048 ushort (4 KB)
  float(*tile2)[65] = (float(*)[65])smem;     // post-loop alias (16640 B)

  const int t = threadIdx.x, lane = t & 63, w = t >> 6;
  const int la = lane & 15, g = lane >> 4;
  const int bid = blockIdx.x;
  const int work = ((bid & 7) << 6) + (bid >> 3);  // XCD swizzle (512 = 8*64)
  const int bx = work >> 2, by = work & 3;

  f32x4 z = {0.f, 0.f, 0.f, 0.f};
  f32x4 acc[4] = {z, z, z, z};

  const float* xp = x + (size_t)(bx * 64 + (t >> 2)) * IND + (t & 3) * 8;
  const ushort* wgh = Wfh + (size_t)(by * 4) * 512;
  const ushort* wgl = Wfl + (size_t)(by * 4) * 512;

  for (int kb = 0; kb < 8; ++kb) {
    __syncthreads();
    // stage x: 64 rows x 32 k fp32 (each thread: 8 floats of one row)
    {
      float4 v0 = *(const float4*)(xp + kb * 32);
      float4 v1 = *(const float4*)(xp + kb * 32 + 4);
      float* dst = &xs[t >> 2][(t & 3) * 8];
      *(float4*)dst = v0;
      *(float4*)(dst + 4) = v1;
    }
    // stage Wf fragments for this kb: 4 ct x 512 ushorts, h and l
    *(short8v*)&wsh[t * 8] = *(const short8v*)(wgh + (size_t)kb * 8192 + t * 8);
    *(short8v*)&wsl[t * 8] = *(const short8v*)(wgl + (size_t)kb * 8192 + t * 8);
    __syncthreads();

    // A fragment from LDS + split-bf16 conversion
    const float* xr = &xs[w * 16 + la][g * 8];
    float4 u0 = *(const float4*)(xr);
    float4 u1 = *(const float4*)(xr + 4);
    const float af[8] = {u0.x, u0.y, u0.z, u0.w, u1.x, u1.y, u1.z, u1.w};
    short8v ah, al;
#pragma unroll
    for (int e = 0; e < 8; ++e) {
      const ushort hb = f2bf(af[e]);
      ah[e] = (short)hb;
      al[e] = (short)f2bf(af[e] - bf2f(hb));
    }
#pragma unroll
    for (int ct = 0; ct < 4; ++ct) {
      const short8v bh = *(const short8v*)&wsh[ct * 512 + lane * 8];
      const short8v bl = *(const short8v*)&wsl[ct * 512 + lane * 8];
      acc[ct] = __builtin_amdgcn_mfma_f32_16x16x32_bf16(ah, bh, acc[ct], 0, 0, 0);
      acc[ct] = __builtin_amdgcn_mfma_f32_16x16x32_bf16(al, bh, acc[ct], 0, 0, 0);
      acc[ct] = __builtin_amdgcn_mfma_f32_16x16x32_bf16(ah, bl, acc[ct], 0, 0, 0);
    }
  }

  const int batch = bx >> 4;
  const int nbase = (bx & 15) * 64 + w * 16;

  // in-register scores (a_s has log2e folded in)
#pragma unroll
  for (int hp2 = 0; hp2 < 2; ++hp2) {
    const int head = by * 2 + hp2;
    const float a0 = a_s[head * 64 + la];
    const float a1 = a_s[head * 64 + 16 + la];
    const float a2 = a_s[head * 64 + 32 + la];
    const float a3 = a_s[head * 64 + 48 + la];
    float s1v[4], s2v[4];
#pragma unroll
    for (int q = 0; q < 4; ++q) {
      s1v[q] = acc[hp2 * 2][q] * a0 + acc[hp2 * 2 + 1][q] * a1;
      s2v[q] = acc[hp2 * 2][q] * a2 + acc[hp2 * 2 + 1][q] * a3;
    }
#pragma unroll
    for (int mask = 1; mask <= 8; mask <<= 1)
#pragma unroll
      for (int q = 0; q < 4; ++q) {
        s1v[q] += __shfl_xor(s1v[q], mask);
        s2v[q] += __shfl_xor(s2v[q], mask);
      }
    if (la == 0) {
#pragma unroll
      for (int q = 0; q < 4; ++q) {
        const size_t o = (size_t)(batch * H + head) * N + nbase + g * 4 + q;
        siT[o] = s1v[q];
        sjT[o] = s2v[q];
      }
    }
  }

  // C -> LDS (alias of xs/ws area; loop reads are done)
  __syncthreads();
#pragma unroll
  for (int ct = 0; ct < 4; ++ct)
#pragma unroll
    for (int q = 0; q < 4; ++q)
      tile2[w * 16 + g * 4 + q][ct * 16 + la] = acc[ct][q];
  __syncthreads();

  // fragment-major bf16 store:
  // hTbF[((bh*32+jt)*64+l)*16 + half*8 + e] = h[jt*32+(l>>4)*8+e][half*16+(l&15)]
  const int jt0 = (bx & 15) * 2;
#pragma unroll
  for (int s = 0; s < 2; ++s) {
    const int gg = t * 2 + s;  // 0..511
    const int head = gg >> 8, rem = gg & 255;
    const int jt_loc = rem >> 7, half = (rem >> 6) & 1, l = rem & 63;
    const int d = half * 16 + (l & 15);
    short8v pk;
#pragma unroll
    for (int e = 0; e < 8; ++e)
      pk[e] = (short)f2bf(tile2[jt_loc * 32 + (l >> 4) * 8 + e][head * 32 + d]);
    const int bh_g = batch * H + by * 2 + head;
    *(short8v*)(hTbF + ((size_t)(bh_g * 32 + jt0 + jt_loc) * 64 + l) * 16 + half * 8) = pk;
  }
}

// ---------------------------------------------------------------------------
// K3: MFMA aggregation. 4 independent waves/block (no LDS/barriers); wave =
// 16 i-rows x full N, 32 j-tiles, 4-deep static pipeline, l via ones-MFMA,
// setprio around MFMA cluster, XCD-swizzled grid (1024 = 8*128).
// ---------------------------------------------------------------------------
__global__ __launch_bounds__(256) void gat_agg(
    const uint* __restrict__ bitsT, const float* __restrict__ siT,
    const float* __restrict__ sjT, const ushort* __restrict__ hTbF,
    float* __restrict__ out) {
  const int t = threadIdx.x;
  const int lane = t & 63, w = t >> 6;
  const int bid = blockIdx.x;
  const int work = ((bid & 7) << 7) + (bid >> 3);  // XCD swizzle
  const int bh = work >> 4;
  const int itg = work & 15;
  const int b = bh >> 3, hh = bh & 7;
  const int i0 = (itg * 4 + w) * 16;
  const int la = lane & 15, g = lane >> 4;
  const int iA = i0 + la;

  const float si_r = siT[(size_t)bh * N + iA];
  const uint* btp = bitsT + (size_t)b * 32 * N + iA;         // + jt*1024
  const float* sjp = sjT + (size_t)bh * N + g * 8;           // + jt*32
  const ushort* hp = hTbF + (size_t)bh * 32768 + lane * 16;  // + jt*1024

  f32x4 acc0 = {0.f, 0.f, 0.f, 0.f}, acc1 = {0.f, 0.f, 0.f, 0.f};
  f32x4 accl = {0.f, 0.f, 0.f, 0.f};
  short8v ones;
#pragma unroll
  for (int e = 0; e < 8; ++e) ones[e] = (short)0x3F80;  // bf16(1.0)

  uint bits0, bits1, bits2, bits3;
  float4 sjA0, sjA1, sjA2, sjA3, sjB0, sjB1, sjB2, sjB3;
  short8v b00, b01, b02, b03, b10, b11, b12, b13;

#define AGG_LOAD(S, JT)                                      \
  bits##S = btp[(size_t)(JT) * 1024];                        \
  sjA##S = *(const float4*)(sjp + (JT) * 32);                \
  sjB##S = *(const float4*)(sjp + (JT) * 32 + 4);            \
  b0##S = *(const short8v*)(hp + (size_t)(JT) * 1024);       \
  b1##S = *(const short8v*)(hp + (size_t)(JT) * 1024 + 8);

#define AGG_COMP(S)                                                           \
  {                                                                           \
    const uint byte_ = (bits##S >> (g * 8)) & 0xffu;                          \
    const float sjv[8] = {sjA##S.x, sjA##S.y, sjA##S.z, sjA##S.w,             \
                          sjB##S.x, sjB##S.y, sjB##S.z, sjB##S.w};            \
    short8v af;                                                               \
    _Pragma("unroll") for (int e = 0; e < 8; ++e) {                           \
      float s = si_r + sjv[e];                                                \
      s = fmaxf(s, 0.2f * s);                                                 \
      s = ((byte_ >> e) & 1u) ? s : -INFINITY;                                \
      af[e] = (short)f2bf(__builtin_amdgcn_exp2f(s));                         \
    }                                                                         \
    __builtin_amdgcn_s_setprio(1);                                            \
    acc0 = __builtin_amdgcn_mfma_f32_16x16x32_bf16(af, b0##S, acc0, 0, 0, 0); \
    acc1 = __builtin_amdgcn_mfma_f32_16x16x32_bf16(af, b1##S, acc1, 0, 0, 0); \
    accl = __builtin_amdgcn_mfma_f32_16x16x32_bf16(af, ones, accl, 0, 0, 0);  \
    __builtin_amdgcn_s_setprio(0);                                            \
  }

  AGG_LOAD(0, 0)
  AGG_LOAD(1, 1)
  AGG_LOAD(2, 2)
  AGG_LOAD(3, 3)
#pragma unroll
  for (int jt = 0; jt < 32; jt += 4) {
    AGG_COMP(0)
    if (jt + 4 < 32) { AGG_LOAD(0, jt + 4) }
    AGG_COMP(1)
    if (jt + 5 < 32) { AGG_LOAD(1, jt + 5) }
    AGG_COMP(2)
    if (jt + 6 < 32) { AGG_LOAD(2, jt + 6) }
    AGG_COMP(3)
    if (jt + 7 < 32) { AGG_LOAD(3, jt + 7) }
  }
#undef AGG_LOAD
#undef AGG_COMP

  float* op = out + ((size_t)(b * N + i0)) * OUTD + hh * D;
#pragma unroll
  for (int r = 0; r < 4; ++r) {
    const int ic = g * 4 + r;
    const float li = accl[r];  // row-sum (identical across cols)
    float v0 = acc0[r] / li;
    v0 = v0 > 0.f ? v0 : expm1f(v0);
    op[(size_t)ic * OUTD + la] = v0;
    float v1 = acc1[r] / li;
    v1 = v1 > 0.f ? v1 : expm1f(v1);
    op[(size_t)ic * OUTD + 16 + la] = v1;
  }
}

extern "C" void kernel_launch(void* const* d_in, const int* in_sizes, int n_in,
                              void* d_out, int out_size, void* d_ws, size_t ws_size,
                              hipStream_t stream) {
  const float* x = (const float*)d_in[0];
  const int* adj = (const int*)d_in[1];
  const float* W = (const float*)d_in[2];
  const float* a = (const float*)d_in[3];
  float* out = (float*)d_out;

  float* ws = (float*)d_ws;
  float* siT = ws;                                   // 65,536 f32
  float* sjT = siT + (size_t)B * N * H;              // 65,536 f32
  uint* bitsT = (uint*)(sjT + (size_t)B * N * H);    // 262,144 u32 (1 MB)
  ushort* hTbF = (ushort*)(bitsT + (size_t)B * 32 * N);  // 2,097,152 bf16 (4 MB)
  ushort* Wfh = hTbF + (size_t)B * N * OUTD;         // 131,072 bf16
  ushort* Wfl = Wfh + 131072;                        // 131,072 bf16
  float* a_s = (float*)(Wfl + 131072);               // 512 f32

  gat_pre<<<32768 + 512, 256, 0, stream>>>(adj, W, a, bitsT, Wfh, Wfl, a_s);
  gat_gemm<<<512, 256, 0, stream>>>(x, Wfh, Wfl, a_s, siT, sjT, hTbF);
  gat_agg<<<1024, 256, 0, stream>>>(bitsT, siT, sjT, hTbF, out);
}

// Round 7
// 53.437 us; speedup vs baseline: 3.9783x; 1.0213x over previous
//
#include <hip/hip_runtime.h>
#include <cmath>

namespace {
constexpr int B = 8, N = 1024, IND = 256, OUTD = 256, H = 8, D = 32;
constexpr float LOG2E = 1.4426950408889634f;
}

typedef __attribute__((ext_vector_type(8))) short short8v;
typedef __attribute__((ext_vector_type(4))) float f32x4;

__device__ inline ushort f2bf(float f) {
  __bf16 b = (__bf16)f;
  return __builtin_bit_cast(ushort, b);
}
__device__ inline float bf2f(ushort u) {
  return __uint_as_float((uint)u << 16);
}

// ---------------------------------------------------------------------------
// K1: heterogeneous pre-pass.
//  blocks [0, 32768): bit-pack adjacency into TRANSPOSED bitsT[b][jt][i].
//  blocks [32768, 33280): W -> split-bf16 MFMA B-fragment-major + a_s.
// ---------------------------------------------------------------------------
__global__ __launch_bounds__(256) void gat_pre(const int* __restrict__ adj,
                                               const float* __restrict__ W,
                                               const float* __restrict__ a,
                                               uint* __restrict__ bitsT,
                                               ushort* __restrict__ Wfh,
                                               ushort* __restrict__ Wfl,
                                               float* __restrict__ a_s) {
  const int bid = blockIdx.x;
  const int t = threadIdx.x;
  if (bid < 32768) {
    const size_t idx = (size_t)bid * 256 + t;
    const int lane = (int)(idx & 63);
    const size_t wid = idx >> 6;
    const int jw = (int)(wid & 15);
    const int i = (int)((wid >> 4) & 1023);
    const int b = (int)(wid >> 14);
    const int v = adj[((size_t)b * N + i) * N + jw * 64 + lane];
    const unsigned long long m = __ballot(v != 0);
    if (lane == 0) {
      bitsT[((size_t)b * 32 + jw * 2) * N + i] = (uint)m;
      bitsT[((size_t)b * 32 + jw * 2 + 1) * N + i] = (uint)(m >> 32);
    }
  } else {
    const int idx = (bid - 32768) * 256 + t;  // 0..131071
    const int e = idx & 7, l = (idx >> 3) & 63, ct = (idx >> 9) & 15,
              kb = idx >> 13;
    const int c = ct * 16 + (l & 15);
    const int k = kb * 32 + (l >> 4) * 8 + e;
    const float v = W[c * IND + k];
    const ushort hi = f2bf(v);
    Wfh[idx] = hi;
    Wfl[idx] = f2bf(v - bf2f(hi));
    if (idx < 512) a_s[idx] = a[idx] * LOG2E;
  }
}

// ---------------------------------------------------------------------------
// K2: GEMM (split-bf16 MFMA, 3-term compensation), x converted in-kernel via
// LDS staging, Wf fragments LDS-deduped across the 4 waves. Epilogue:
// in-register scores + fragment-major hTbF store.
// Block = 256 thr = 4 row-stacked waves = 64 rows x 64 cols.
// grid = 512 (XCD-swizzled -> bx in 0..127, by in 0..3).
// ---------------------------------------------------------------------------
__global__ __launch_bounds__(256) void gat_gemm(
    const float* __restrict__ x, const ushort* __restrict__ Wfh,
    const ushort* __restrict__ Wfl, const float* __restrict__ a_s,
    float* __restrict__ siT, float* __restrict__ sjT,
    ushort* __restrict__ hTbF) {
  __shared__ __align__(16) char smem[17664];
  float(*xs)[36] = (float(*)[36])smem;        // 64 x 36 f32 (9216 B)
  ushort* wsh = (ushort*)(smem + 9216);       // 2048 ushort (4 KB)
  ushort* wsl = (ushort*)(smem + 13312);      // 2048 ushort (4 KB)
  float(*tile2)[65] = (float(*)[65])smem;     // post-loop alias (16640 B)

  const int t = threadIdx.x, lane = t & 63, w = t >> 6;
  const int la = lane & 15, g = lane >> 4;
  const int bid = blockIdx.x;
  const int work = ((bid & 7) << 6) + (bid >> 3);  // XCD swizzle (512 = 8*64)
  const int bx = work >> 2, by = work & 3;

  f32x4 z = {0.f, 0.f, 0.f, 0.f};
  f32x4 acc[4] = {z, z, z, z};

  const float* xp = x + (size_t)(bx * 64 + (t >> 2)) * IND + (t & 3) * 8;
  const ushort* wgh = Wfh + (size_t)(by * 4) * 512;
  const ushort* wgl = Wfl + (size_t)(by * 4) * 512;

  for (int kb = 0; kb < 8; ++kb) {
    __syncthreads();
    {
      float4 v0 = *(const float4*)(xp + kb * 32);
      float4 v1 = *(const float4*)(xp + kb * 32 + 4);
      float* dst = &xs[t >> 2][(t & 3) * 8];
      *(float4*)dst = v0;
      *(float4*)(dst + 4) = v1;
    }
    *(short8v*)&wsh[t * 8] = *(const short8v*)(wgh + (size_t)kb * 8192 + t * 8);
    *(short8v*)&wsl[t * 8] = *(const short8v*)(wgl + (size_t)kb * 8192 + t * 8);
    __syncthreads();

    const float* xr = &xs[w * 16 + la][g * 8];
    float4 u0 = *(const float4*)(xr);
    float4 u1 = *(const float4*)(xr + 4);
    const float af[8] = {u0.x, u0.y, u0.z, u0.w, u1.x, u1.y, u1.z, u1.w};
    short8v ah, al;
#pragma unroll
    for (int e = 0; e < 8; ++e) {
      const ushort hb = f2bf(af[e]);
      ah[e] = (short)hb;
      al[e] = (short)f2bf(af[e] - bf2f(hb));
    }
#pragma unroll
    for (int ct = 0; ct < 4; ++ct) {
      const short8v bh = *(const short8v*)&wsh[ct * 512 + lane * 8];
      const short8v bl = *(const short8v*)&wsl[ct * 512 + lane * 8];
      acc[ct] = __builtin_amdgcn_mfma_f32_16x16x32_bf16(ah, bh, acc[ct], 0, 0, 0);
      acc[ct] = __builtin_amdgcn_mfma_f32_16x16x32_bf16(al, bh, acc[ct], 0, 0, 0);
      acc[ct] = __builtin_amdgcn_mfma_f32_16x16x32_bf16(ah, bl, acc[ct], 0, 0, 0);
    }
  }

  const int batch = bx >> 4;
  const int nbase = (bx & 15) * 64 + w * 16;

#pragma unroll
  for (int hp2 = 0; hp2 < 2; ++hp2) {
    const int head = by * 2 + hp2;
    const float a0 = a_s[head * 64 + la];
    const float a1 = a_s[head * 64 + 16 + la];
    const float a2 = a_s[head * 64 + 32 + la];
    const float a3 = a_s[head * 64 + 48 + la];
    float s1v[4], s2v[4];
#pragma unroll
    for (int q = 0; q < 4; ++q) {
      s1v[q] = acc[hp2 * 2][q] * a0 + acc[hp2 * 2 + 1][q] * a1;
      s2v[q] = acc[hp2 * 2][q] * a2 + acc[hp2 * 2 + 1][q] * a3;
    }
#pragma unroll
    for (int mask = 1; mask <= 8; mask <<= 1)
#pragma unroll
      for (int q = 0; q < 4; ++q) {
        s1v[q] += __shfl_xor(s1v[q], mask);
        s2v[q] += __shfl_xor(s2v[q], mask);
      }
    if (la == 0) {
#pragma unroll
      for (int q = 0; q < 4; ++q) {
        const size_t o = (size_t)(batch * H + head) * N + nbase + g * 4 + q;
        siT[o] = s1v[q];
        sjT[o] = s2v[q];
      }
    }
  }

  __syncthreads();
#pragma unroll
  for (int ct = 0; ct < 4; ++ct)
#pragma unroll
    for (int q = 0; q < 4; ++q)
      tile2[w * 16 + g * 4 + q][ct * 16 + la] = acc[ct][q];
  __syncthreads();

  const int jt0 = (bx & 15) * 2;
#pragma unroll
  for (int s = 0; s < 2; ++s) {
    const int gg = t * 2 + s;  // 0..511
    const int head = gg >> 8, rem = gg & 255;
    const int jt_loc = rem >> 7, half = (rem >> 6) & 1, l = rem & 63;
    const int d = half * 16 + (l & 15);
    short8v pk;
#pragma unroll
    for (int e = 0; e < 8; ++e)
      pk[e] = (short)f2bf(tile2[jt_loc * 32 + (l >> 4) * 8 + e][head * 32 + d]);
    const int bh_g = batch * H + by * 2 + head;
    *(short8v*)(hTbF + ((size_t)(bh_g * 32 + jt0 + jt_loc) * 64 + l) * 16 + half * 8) = pk;
  }
}

// ---------------------------------------------------------------------------
// K3: MFMA aggregation, 2-way j-split for full occupancy.
// Block = 256 thr = 4 waves: iw = w&1 (i-half), jq = w>>1 (j-half).
// Wave = 16 i-rows x 16 j-tiles, 2-deep pipeline (VGPR <= 64 for 8 waves/
// SIMD). Partials combined via LDS (one barrier). l via ones-MFMA.
// grid = 2048 (XCD-swizzled, 8*256; one bh's 32 blocks share an XCD).
// ---------------------------------------------------------------------------
__global__ __launch_bounds__(256) void gat_agg(
    const uint* __restrict__ bitsT, const float* __restrict__ siT,
    const float* __restrict__ sjT, const ushort* __restrict__ hTbF,
    float* __restrict__ out) {
  __shared__ float part[2][64][13];  // [iw][lane][12], padded
  const int t = threadIdx.x;
  const int lane = t & 63, w = t >> 6;
  const int iw = w & 1, jq = w >> 1;
  const int bid = blockIdx.x;
  const int work = ((bid & 7) << 8) + (bid >> 3);  // XCD swizzle (2048 = 8*256)
  const int bh = work >> 5;
  const int itg = work & 31;
  const int b = bh >> 3, hh = bh & 7;
  const int i0 = itg * 32 + iw * 16;
  const int la = lane & 15, g = lane >> 4;
  const int iA = i0 + la;

  const float si_r = siT[(size_t)bh * N + iA];
  const uint* btp = bitsT + (size_t)b * 32 * N + (size_t)jq * 16 * N + iA;
  const float* sjp = sjT + (size_t)bh * N + jq * 512 + g * 8;
  const ushort* hp = hTbF + (size_t)bh * 32768 + (size_t)jq * 16384 + lane * 16;

  f32x4 acc0 = {0.f, 0.f, 0.f, 0.f}, acc1 = {0.f, 0.f, 0.f, 0.f};
  f32x4 accl = {0.f, 0.f, 0.f, 0.f};
  short8v ones;
#pragma unroll
  for (int e = 0; e < 8; ++e) ones[e] = (short)0x3F80;  // bf16(1.0)

  uint bits0, bits1;
  float4 sjA0, sjB0, sjA1, sjB1;
  short8v b00, b10, b01, b11;

#define AGG_LOAD(S, JT)                                      \
  bits##S = btp[(size_t)(JT)*1024];                          \
  sjA##S = *(const float4*)(sjp + (JT) * 32);                \
  sjB##S = *(const float4*)(sjp + (JT) * 32 + 4);            \
  b0##S = *(const short8v*)(hp + (size_t)(JT)*1024);         \
  b1##S = *(const short8v*)(hp + (size_t)(JT)*1024 + 8);

#define AGG_COMP(S)                                                           \
  {                                                                           \
    const uint byte_ = (bits##S >> (g * 8)) & 0xffu;                          \
    const float sjv[8] = {sjA##S.x, sjA##S.y, sjA##S.z, sjA##S.w,             \
                          sjB##S.x, sjB##S.y, sjB##S.z, sjB##S.w};            \
    short8v af;                                                               \
    _Pragma("unroll") for (int e = 0; e < 8; ++e) {                           \
      float s = si_r + sjv[e];                                                \
      s = fmaxf(s, 0.2f * s);                                                 \
      s = ((byte_ >> e) & 1u) ? s : -INFINITY;                                \
      af[e] = (short)f2bf(__builtin_amdgcn_exp2f(s));                         \
    }                                                                         \
    __builtin_amdgcn_s_setprio(1);                                            \
    acc0 = __builtin_amdgcn_mfma_f32_16x16x32_bf16(af, b0##S, acc0, 0, 0, 0); \
    acc1 = __builtin_amdgcn_mfma_f32_16x16x32_bf16(af, b1##S, acc1, 0, 0, 0); \
    accl = __builtin_amdgcn_mfma_f32_16x16x32_bf16(af, ones, accl, 0, 0, 0);  \
    __builtin_amdgcn_s_setprio(0);                                            \
  }

  AGG_LOAD(0, 0)
  AGG_LOAD(1, 1)
#pragma unroll
  for (int jt = 0; jt < 16; jt += 2) {
    AGG_COMP(0)
    if (jt + 2 < 16) { AGG_LOAD(0, jt + 2) }
    AGG_COMP(1)
    if (jt + 3 < 16) { AGG_LOAD(1, jt + 3) }
  }
#undef AGG_LOAD
#undef AGG_COMP

  // combine j-halves: jq=1 stores partials, jq=0 adds + epilogue
  if (jq == 1) {
    float* p = part[iw][lane];
#pragma unroll
    for (int k = 0; k < 4; ++k) {
      p[k] = acc0[k];
      p[4 + k] = acc1[k];
      p[8 + k] = accl[k];
    }
  }
  __syncthreads();
  if (jq == 0) {
    const float* p = part[iw][lane];
#pragma unroll
    for (int k = 0; k < 4; ++k) {
      acc0[k] += p[k];
      acc1[k] += p[4 + k];
      accl[k] += p[8 + k];
    }
    float* op = out + ((size_t)(b * N + i0)) * OUTD + hh * D;
#pragma unroll
    for (int r = 0; r < 4; ++r) {
      const int ic = g * 4 + r;
      const float li = accl[r];  // row-sum (identical across cols)
      float v0 = acc0[r] / li;
      v0 = v0 > 0.f ? v0 : expm1f(v0);
      op[(size_t)ic * OUTD + la] = v0;
      float v1 = acc1[r] / li;
      v1 = v1 > 0.f ? v1 : expm1f(v1);
      op[(size_t)ic * OUTD + 16 + la] = v1;
    }
  }
}

extern "C" void kernel_launch(void* const* d_in, const int* in_sizes, int n_in,
                              void* d_out, int out_size, void* d_ws, size_t ws_size,
                              hipStream_t stream) {
  const float* x = (const float*)d_in[0];
  const int* adj = (const int*)d_in[1];
  const float* W = (const float*)d_in[2];
  const float* a = (const float*)d_in[3];
  float* out = (float*)d_out;

  float* ws = (float*)d_ws;
  float* siT = ws;                                   // 65,536 f32
  float* sjT = siT + (size_t)B * N * H;              // 65,536 f32
  uint* bitsT = (uint*)(sjT + (size_t)B * N * H);    // 262,144 u32 (1 MB)
  ushort* hTbF = (ushort*)(bitsT + (size_t)B * 32 * N);  // 2,097,152 bf16 (4 MB)
  ushort* Wfh = hTbF + (size_t)B * N * OUTD;         // 131,072 bf16
  ushort* Wfl = Wfh + 131072;                        // 131,072 bf16
  float* a_s = (float*)(Wfl + 131072);               // 512 f32

  gat_pre<<<32768 + 512, 256, 0, stream>>>(adj, W, a, bitsT, Wfh, Wfl, a_s);
  gat_gemm<<<512, 256, 0, stream>>>(x, Wfh, Wfl, a_s, siT, sjT, hTbF);
  gat_agg<<<2048, 256, 0, stream>>>(bitsT, siT, sjT, hTbF, out);
}

// Round 8
// 46.707 us; speedup vs baseline: 4.5515x; 1.1441x over previous
//
#include <hip/hip_runtime.h>
#include <cmath>

namespace {
constexpr int B = 8, N = 1024, IND = 256, OUTD = 256, H = 8, D = 32;
constexpr float LOG2E = 1.4426950408889634f;
}

typedef __attribute__((ext_vector_type(8))) short short8v;
typedef __attribute__((ext_vector_type(4))) float f32x4;

__device__ inline ushort f2bf(float f) {
  __bf16 b = (__bf16)f;
  return __builtin_bit_cast(ushort, b);
}
__device__ inline float bf2f(ushort u) {
  return __uint_as_float((uint)u << 16);
}

// ---------------------------------------------------------------------------
// K1: pre-pass, dense grid (G11: few blocks, fat waves).
//  blocks [0, 2048): bit-pack adjacency -> TRANSPOSED bitsT[b][jt][i].
//    One wave per (b,i) row: 4 x int4 per lane (1KB/wave coalesced),
//    nibble -> 8-lane OR-reduce (3 shfl_xor) -> one uint per 32 j.
//  blocks [2048, 2560): W -> split-bf16 MFMA B-fragment-major + a_s.
// ---------------------------------------------------------------------------
__global__ __launch_bounds__(256) void gat_pre(const int* __restrict__ adj,
                                               const float* __restrict__ W,
                                               const float* __restrict__ a,
                                               uint* __restrict__ bitsT,
                                               ushort* __restrict__ Wfh,
                                               ushort* __restrict__ Wfl,
                                               float* __restrict__ a_s) {
  const int bid = blockIdx.x;
  const int t = threadIdx.x;
  if (bid < 2048) {
    const int lane = t & 63, w = t >> 6;
    const int wid = bid * 4 + w;  // 0..8191 = b*N + i
    const int b = wid >> 10, i = wid & 1023;
    const int4* ap = (const int4*)(adj + ((size_t)b * N + i) * N);
#pragma unroll
    for (int c = 0; c < 4; ++c) {
      const int4 v = ap[c * 64 + lane];
      uint val = (v.x != 0 ? 1u : 0u) | (v.y != 0 ? 2u : 0u) |
                 (v.z != 0 ? 4u : 0u) | (v.w != 0 ? 8u : 0u);
      val <<= (lane & 7) * 4;
      val |= (uint)__shfl_xor((int)val, 1);
      val |= (uint)__shfl_xor((int)val, 2);
      val |= (uint)__shfl_xor((int)val, 4);
      if ((lane & 7) == 0) {
        const int jt = c * 8 + (lane >> 3);
        bitsT[((size_t)b * 32 + jt) * N + i] = val;
      }
    }
  } else {
    const int idx = (bid - 2048) * 256 + t;  // 0..131071
    const int e = idx & 7, l = (idx >> 3) & 63, ct = (idx >> 9) & 15,
              kb = idx >> 13;
    const int c = ct * 16 + (l & 15);
    const int k = kb * 32 + (l >> 4) * 8 + e;
    const float v = W[c * IND + k];
    const ushort hi = f2bf(v);
    Wfh[idx] = hi;
    Wfl[idx] = f2bf(v - bf2f(hi));
    if (idx < 512) a_s[idx] = a[idx] * LOG2E;
  }
}

// ---------------------------------------------------------------------------
// K2: GEMM (split-bf16 MFMA, 3-term compensation), x converted in-kernel via
// LDS staging, Wf fragments LDS-deduped across the 4 waves. Epilogue:
// in-register scores + fragment-major hTbF store. (unchanged from round 7)
// ---------------------------------------------------------------------------
__global__ __launch_bounds__(256) void gat_gemm(
    const float* __restrict__ x, const ushort* __restrict__ Wfh,
    const ushort* __restrict__ Wfl, const float* __restrict__ a_s,
    float* __restrict__ siT, float* __restrict__ sjT,
    ushort* __restrict__ hTbF) {
  __shared__ __align__(16) char smem[17664];
  float(*xs)[36] = (float(*)[36])smem;        // 64 x 36 f32 (9216 B)
  ushort* wsh = (ushort*)(smem + 9216);       // 2048 ushort (4 KB)
  ushort* wsl = (ushort*)(smem + 13312);      // 2048 ushort (4 KB)
  float(*tile2)[65] = (float(*)[65])smem;     // post-loop alias (16640 B)

  const int t = threadIdx.x, lane = t & 63, w = t >> 6;
  const int la = lane & 15, g = lane >> 4;
  const int bid = blockIdx.x;
  const int work = ((bid & 7) << 6) + (bid >> 3);  // XCD swizzle (512 = 8*64)
  const int bx = work >> 2, by = work & 3;

  f32x4 z = {0.f, 0.f, 0.f, 0.f};
  f32x4 acc[4] = {z, z, z, z};

  const float* xp = x + (size_t)(bx * 64 + (t >> 2)) * IND + (t & 3) * 8;
  const ushort* wgh = Wfh + (size_t)(by * 4) * 512;
  const ushort* wgl = Wfl + (size_t)(by * 4) * 512;

  for (int kb = 0; kb < 8; ++kb) {
    __syncthreads();
    {
      float4 v0 = *(const float4*)(xp + kb * 32);
      float4 v1 = *(const float4*)(xp + kb * 32 + 4);
      float* dst = &xs[t >> 2][(t & 3) * 8];
      *(float4*)dst = v0;
      *(float4*)(dst + 4) = v1;
    }
    *(short8v*)&wsh[t * 8] = *(const short8v*)(wgh + (size_t)kb * 8192 + t * 8);
    *(short8v*)&wsl[t * 8] = *(const short8v*)(wgl + (size_t)kb * 8192 + t * 8);
    __syncthreads();

    const float* xr = &xs[w * 16 + la][g * 8];
    float4 u0 = *(const float4*)(xr);
    float4 u1 = *(const float4*)(xr + 4);
    const float af[8] = {u0.x, u0.y, u0.z, u0.w, u1.x, u1.y, u1.z, u1.w};
    short8v ah, al;
#pragma unroll
    for (int e = 0; e < 8; ++e) {
      const ushort hb = f2bf(af[e]);
      ah[e] = (short)hb;
      al[e] = (short)f2bf(af[e] - bf2f(hb));
    }
#pragma unroll
    for (int ct = 0; ct < 4; ++ct) {
      const short8v bh = *(const short8v*)&wsh[ct * 512 + lane * 8];
      const short8v bl = *(const short8v*)&wsl[ct * 512 + lane * 8];
      acc[ct] = __builtin_amdgcn_mfma_f32_16x16x32_bf16(ah, bh, acc[ct], 0, 0, 0);
      acc[ct] = __builtin_amdgcn_mfma_f32_16x16x32_bf16(al, bh, acc[ct], 0, 0, 0);
      acc[ct] = __builtin_amdgcn_mfma_f32_16x16x32_bf16(ah, bl, acc[ct], 0, 0, 0);
    }
  }

  const int batch = bx >> 4;
  const int nbase = (bx & 15) * 64 + w * 16;

#pragma unroll
  for (int hp2 = 0; hp2 < 2; ++hp2) {
    const int head = by * 2 + hp2;
    const float a0 = a_s[head * 64 + la];
    const float a1 = a_s[head * 64 + 16 + la];
    const float a2 = a_s[head * 64 + 32 + la];
    const float a3 = a_s[head * 64 + 48 + la];
    float s1v[4], s2v[4];
#pragma unroll
    for (int q = 0; q < 4; ++q) {
      s1v[q] = acc[hp2 * 2][q] * a0 + acc[hp2 * 2 + 1][q] * a1;
      s2v[q] = acc[hp2 * 2][q] * a2 + acc[hp2 * 2 + 1][q] * a3;
    }
#pragma unroll
    for (int mask = 1; mask <= 8; mask <<= 1)
#pragma unroll
      for (int q = 0; q < 4; ++q) {
        s1v[q] += __shfl_xor(s1v[q], mask);
        s2v[q] += __shfl_xor(s2v[q], mask);
      }
    if (la == 0) {
#pragma unroll
      for (int q = 0; q < 4; ++q) {
        const size_t o = (size_t)(batch * H + head) * N + nbase + g * 4 + q;
        siT[o] = s1v[q];
        sjT[o] = s2v[q];
      }
    }
  }

  __syncthreads();
#pragma unroll
  for (int ct = 0; ct < 4; ++ct)
#pragma unroll
    for (int q = 0; q < 4; ++q)
      tile2[w * 16 + g * 4 + q][ct * 16 + la] = acc[ct][q];
  __syncthreads();

  const int jt0 = (bx & 15) * 2;
#pragma unroll
  for (int s = 0; s < 2; ++s) {
    const int gg = t * 2 + s;  // 0..511
    const int head = gg >> 8, rem = gg & 255;
    const int jt_loc = rem >> 7, half = (rem >> 6) & 1, l = rem & 63;
    const int d = half * 16 + (l & 15);
    short8v pk;
#pragma unroll
    for (int e = 0; e < 8; ++e)
      pk[e] = (short)f2bf(tile2[jt_loc * 32 + (l >> 4) * 8 + e][head * 32 + d]);
    const int bh_g = batch * H + by * 2 + head;
    *(short8v*)(hTbF + ((size_t)(bh_g * 32 + jt0 + jt_loc) * 64 + l) * 16 + half * 8) = pk;
  }
}

// ---------------------------------------------------------------------------
// K3: MFMA aggregation, 2-way j-split (unchanged from round 7).
// ---------------------------------------------------------------------------
__global__ __launch_bounds__(256) void gat_agg(
    const uint* __restrict__ bitsT, const float* __restrict__ siT,
    const float* __restrict__ sjT, const ushort* __restrict__ hTbF,
    float* __restrict__ out) {
  __shared__ float part[2][64][13];  // [iw][lane][12], padded
  const int t = threadIdx.x;
  const int lane = t & 63, w = t >> 6;
  const int iw = w & 1, jq = w >> 1;
  const int bid = blockIdx.x;
  const int work = ((bid & 7) << 8) + (bid >> 3);  // XCD swizzle (2048 = 8*256)
  const int bh = work >> 5;
  const int itg = work & 31;
  const int b = bh >> 3, hh = bh & 7;
  const int i0 = itg * 32 + iw * 16;
  const int la = lane & 15, g = lane >> 4;
  const int iA = i0 + la;

  const float si_r = siT[(size_t)bh * N + iA];
  const uint* btp = bitsT + (size_t)b * 32 * N + (size_t)jq * 16 * N + iA;
  const float* sjp = sjT + (size_t)bh * N + jq * 512 + g * 8;
  const ushort* hp = hTbF + (size_t)bh * 32768 + (size_t)jq * 16384 + lane * 16;

  f32x4 acc0 = {0.f, 0.f, 0.f, 0.f}, acc1 = {0.f, 0.f, 0.f, 0.f};
  f32x4 accl = {0.f, 0.f, 0.f, 0.f};
  short8v ones;
#pragma unroll
  for (int e = 0; e < 8; ++e) ones[e] = (short)0x3F80;  // bf16(1.0)

  uint bits0, bits1;
  float4 sjA0, sjB0, sjA1, sjB1;
  short8v b00, b10, b01, b11;

#define AGG_LOAD(S, JT)                                      \
  bits##S = btp[(size_t)(JT)*1024];                          \
  sjA##S = *(const float4*)(sjp + (JT) * 32);                \
  sjB##S = *(const float4*)(sjp + (JT) * 32 + 4);            \
  b0##S = *(const short8v*)(hp + (size_t)(JT)*1024);         \
  b1##S = *(const short8v*)(hp + (size_t)(JT)*1024 + 8);

#define AGG_COMP(S)                                                           \
  {                                                                           \
    const uint byte_ = (bits##S >> (g * 8)) & 0xffu;                          \
    const float sjv[8] = {sjA##S.x, sjA##S.y, sjA##S.z, sjA##S.w,             \
                          sjB##S.x, sjB##S.y, sjB##S.z, sjB##S.w};            \
    short8v af;                                                               \
    _Pragma("unroll") for (int e = 0; e < 8; ++e) {                           \
      float s = si_r + sjv[e];                                                \
      s = fmaxf(s, 0.2f * s);                                                 \
      s = ((byte_ >> e) & 1u) ? s : -INFINITY;                                \
      af[e] = (short)f2bf(__builtin_amdgcn_exp2f(s));                         \
    }                                                                         \
    __builtin_amdgcn_s_setprio(1);                                            \
    acc0 = __builtin_amdgcn_mfma_f32_16x16x32_bf16(af, b0##S, acc0, 0, 0, 0); \
    acc1 = __builtin_amdgcn_mfma_f32_16x16x32_bf16(af, b1##S, acc1, 0, 0, 0); \
    accl = __builtin_amdgcn_mfma_f32_16x16x32_bf16(af, ones, accl, 0, 0, 0);  \
    __builtin_amdgcn_s_setprio(0);                                            \
  }

  AGG_LOAD(0, 0)
  AGG_LOAD(1, 1)
#pragma unroll
  for (int jt = 0; jt < 16; jt += 2) {
    AGG_COMP(0)
    if (jt + 2 < 16) { AGG_LOAD(0, jt + 2) }
    AGG_COMP(1)
    if (jt + 3 < 16) { AGG_LOAD(1, jt + 3) }
  }
#undef AGG_LOAD
#undef AGG_COMP

  if (jq == 1) {
    float* p = part[iw][lane];
#pragma unroll
    for (int k = 0; k < 4; ++k) {
      p[k] = acc0[k];
      p[4 + k] = acc1[k];
      p[8 + k] = accl[k];
    }
  }
  __syncthreads();
  if (jq == 0) {
    const float* p = part[iw][lane];
#pragma unroll
    for (int k = 0; k < 4; ++k) {
      acc0[k] += p[k];
      acc1[k] += p[4 + k];
      accl[k] += p[8 + k];
    }
    float* op = out + ((size_t)(b * N + i0)) * OUTD + hh * D;
#pragma unroll
    for (int r = 0; r < 4; ++r) {
      const int ic = g * 4 + r;
      const float li = accl[r];  // row-sum (identical across cols)
      float v0 = acc0[r] / li;
      v0 = v0 > 0.f ? v0 : expm1f(v0);
      op[(size_t)ic * OUTD + la] = v0;
      float v1 = acc1[r] / li;
      v1 = v1 > 0.f ? v1 : expm1f(v1);
      op[(size_t)ic * OUTD + 16 + la] = v1;
    }
  }
}

extern "C" void kernel_launch(void* const* d_in, const int* in_sizes, int n_in,
                              void* d_out, int out_size, void* d_ws, size_t ws_size,
                              hipStream_t stream) {
  const float* x = (const float*)d_in[0];
  const int* adj = (const int*)d_in[1];
  const float* W = (const float*)d_in[2];
  const float* a = (const float*)d_in[3];
  float* out = (float*)d_out;

  float* ws = (float*)d_ws;
  float* siT = ws;                                   // 65,536 f32
  float* sjT = siT + (size_t)B * N * H;              // 65,536 f32
  uint* bitsT = (uint*)(sjT + (size_t)B * N * H);    // 262,144 u32 (1 MB)
  ushort* hTbF = (ushort*)(bitsT + (size_t)B * 32 * N);  // 2,097,152 bf16 (4 MB)
  ushort* Wfh = hTbF + (size_t)B * N * OUTD;         // 131,072 bf16
  ushort* Wfl = Wfh + 131072;                        // 131,072 bf16
  float* a_s = (float*)(Wfl + 131072);               // 512 f32

  gat_pre<<<2048 + 512, 256, 0, stream>>>(adj, W, a, bitsT, Wfh, Wfl, a_s);
  gat_gemm<<<512, 256, 0, stream>>>(x, Wfh, Wfl, a_s, siT, sjT, hTbF);
  gat_agg<<<2048, 256, 0, stream>>>(bitsT, siT, sjT, hTbF, out);
}

// Round 9
// 42.113 us; speedup vs baseline: 5.0481x; 1.1091x over previous
//
#include <hip/hip_runtime.h>
#include <cmath>

namespace {
constexpr int B = 8, N = 1024, IND = 256, OUTD = 256, H = 8, D = 32;
constexpr float LOG2E = 1.4426950408889634f;
}

typedef __attribute__((ext_vector_type(8))) short short8v;
typedef __attribute__((ext_vector_type(4))) float f32x4;

__device__ inline ushort f2bf(float f) {
  __bf16 b = (__bf16)f;
  return __builtin_bit_cast(ushort, b);
}
__device__ inline float bf2f(ushort u) {
  return __uint_as_float((uint)u << 16);
}

// ---------------------------------------------------------------------------
// K1: heterogeneous {GEMM || bitpack}, 2560 blocks.
//  bid < 512: GEMM (split-bf16 MFMA, 3-term compensation). W is split+swizzled
//    INLINE during LDS staging (no Wf buffers, no pre-kernel dependency).
//    Epilogue: in-register scores (a * log2e read directly) + fragment-major
//    hTbF store. Block = 4 row-stacked waves = 64 rows x 64 cols.
//  bid >= 512: dense bitpack of adj -> TRANSPOSED bitsT[b][jt][i].
//    One wave per (b,i) row: 4 x int4/lane, nibble OR-reduce via shfl_xor.
// ---------------------------------------------------------------------------
__global__ __launch_bounds__(256) void gat_k1(
    const float* __restrict__ x, const float* __restrict__ W,
    const float* __restrict__ a, const int* __restrict__ adj,
    uint* __restrict__ bitsT, float* __restrict__ siT,
    float* __restrict__ sjT, ushort* __restrict__ hTbF) {
  const int bid = blockIdx.x;
  const int t = threadIdx.x;

  if (bid >= 512) {
    // ---- bitpack ----
    const int lane = t & 63, w = t >> 6;
    const int wid = (bid - 512) * 4 + w;  // 0..8191 = b*N + i
    const int b = wid >> 10, i = wid & 1023;
    const int4* ap = (const int4*)(adj + ((size_t)b * N + i) * N);
#pragma unroll
    for (int c = 0; c < 4; ++c) {
      const int4 v = ap[c * 64 + lane];
      uint val = (v.x != 0 ? 1u : 0u) | (v.y != 0 ? 2u : 0u) |
                 (v.z != 0 ? 4u : 0u) | (v.w != 0 ? 8u : 0u);
      val <<= (lane & 7) * 4;
      val |= (uint)__shfl_xor((int)val, 1);
      val |= (uint)__shfl_xor((int)val, 2);
      val |= (uint)__shfl_xor((int)val, 4);
      if ((lane & 7) == 0) {
        const int jt = c * 8 + (lane >> 3);
        bitsT[((size_t)b * 32 + jt) * N + i] = val;
      }
    }
    return;
  }

  // ---- GEMM ----
  __shared__ __align__(16) char smem[17664];
  float(*xs)[36] = (float(*)[36])smem;     // 64 x 36 f32 (9216 B)
  ushort* wsh = (ushort*)(smem + 9216);    // 2048 ushort (4 KB)
  ushort* wsl = (ushort*)(smem + 13312);   // 2048 ushort (4 KB)
  float(*tile2)[65] = (float(*)[65])smem;  // post-loop alias (16640 B)

  const int lane = t & 63, w = t >> 6;
  const int la = lane & 15, g = lane >> 4;
  const int work = ((bid & 7) << 6) + (bid >> 3);  // XCD swizzle (512 = 8*64)
  const int bx = work >> 2, by = work & 3;

  f32x4 z = {0.f, 0.f, 0.f, 0.f};
  f32x4 acc[4] = {z, z, z, z};

  const float* xp = x + (size_t)(bx * 64 + (t >> 2)) * IND + (t & 3) * 8;
  // inline W staging coords: thread t -> (ct = t>>6, l = t&63)
  const int w_c = by * 64 + (t >> 6) * 16 + (t & 15);
  const int w_k0 = ((t >> 4) & 3) * 8;
  const float* wp = W + (size_t)w_c * IND + w_k0;

  for (int kb = 0; kb < 8; ++kb) {
    __syncthreads();
    {
      float4 v0 = *(const float4*)(xp + kb * 32);
      float4 v1 = *(const float4*)(xp + kb * 32 + 4);
      float* dst = &xs[t >> 2][(t & 3) * 8];
      *(float4*)dst = v0;
      *(float4*)(dst + 4) = v1;
    }
    {
      // stage + split + swizzle W for this kb (bit-identical to pre-kernel)
      float4 v0 = *(const float4*)(wp + kb * 32);
      float4 v1 = *(const float4*)(wp + kb * 32 + 4);
      const float wf[8] = {v0.x, v0.y, v0.z, v0.w, v1.x, v1.y, v1.z, v1.w};
      short8v ph, pl;
#pragma unroll
      for (int e = 0; e < 8; ++e) {
        const ushort hi = f2bf(wf[e]);
        ph[e] = (short)hi;
        pl[e] = (short)f2bf(wf[e] - bf2f(hi));
      }
      *(short8v*)&wsh[t * 8] = ph;
      *(short8v*)&wsl[t * 8] = pl;
    }
    __syncthreads();

    const float* xr = &xs[w * 16 + la][g * 8];
    float4 u0 = *(const float4*)(xr);
    float4 u1 = *(const float4*)(xr + 4);
    const float af[8] = {u0.x, u0.y, u0.z, u0.w, u1.x, u1.y, u1.z, u1.w};
    short8v ah, al;
#pragma unroll
    for (int e = 0; e < 8; ++e) {
      const ushort hb = f2bf(af[e]);
      ah[e] = (short)hb;
      al[e] = (short)f2bf(af[e] - bf2f(hb));
    }
#pragma unroll
    for (int ct = 0; ct < 4; ++ct) {
      const short8v bh = *(const short8v*)&wsh[ct * 512 + lane * 8];
      const short8v bl = *(const short8v*)&wsl[ct * 512 + lane * 8];
      acc[ct] = __builtin_amdgcn_mfma_f32_16x16x32_bf16(ah, bh, acc[ct], 0, 0, 0);
      acc[ct] = __builtin_amdgcn_mfma_f32_16x16x32_bf16(al, bh, acc[ct], 0, 0, 0);
      acc[ct] = __builtin_amdgcn_mfma_f32_16x16x32_bf16(ah, bl, acc[ct], 0, 0, 0);
    }
  }

  const int batch = bx >> 4;
  const int nbase = (bx & 15) * 64 + w * 16;

  // in-register scores; log2e folded at read of a
#pragma unroll
  for (int hp2 = 0; hp2 < 2; ++hp2) {
    const int head = by * 2 + hp2;
    const float a0 = a[head * 64 + la] * LOG2E;
    const float a1 = a[head * 64 + 16 + la] * LOG2E;
    const float a2 = a[head * 64 + 32 + la] * LOG2E;
    const float a3 = a[head * 64 + 48 + la] * LOG2E;
    float s1v[4], s2v[4];
#pragma unroll
    for (int q = 0; q < 4; ++q) {
      s1v[q] = acc[hp2 * 2][q] * a0 + acc[hp2 * 2 + 1][q] * a1;
      s2v[q] = acc[hp2 * 2][q] * a2 + acc[hp2 * 2 + 1][q] * a3;
    }
#pragma unroll
    for (int mask = 1; mask <= 8; mask <<= 1)
#pragma unroll
      for (int q = 0; q < 4; ++q) {
        s1v[q] += __shfl_xor(s1v[q], mask);
        s2v[q] += __shfl_xor(s2v[q], mask);
      }
    if (la == 0) {
#pragma unroll
      for (int q = 0; q < 4; ++q) {
        const size_t o = (size_t)(batch * H + head) * N + nbase + g * 4 + q;
        siT[o] = s1v[q];
        sjT[o] = s2v[q];
      }
    }
  }

  __syncthreads();
#pragma unroll
  for (int ct = 0; ct < 4; ++ct)
#pragma unroll
    for (int q = 0; q < 4; ++q)
      tile2[w * 16 + g * 4 + q][ct * 16 + la] = acc[ct][q];
  __syncthreads();

  const int jt0 = (bx & 15) * 2;
#pragma unroll
  for (int s = 0; s < 2; ++s) {
    const int gg = t * 2 + s;  // 0..511
    const int head = gg >> 8, rem = gg & 255;
    const int jt_loc = rem >> 7, half = (rem >> 6) & 1, l = rem & 63;
    const int d = half * 16 + (l & 15);
    short8v pk;
#pragma unroll
    for (int e = 0; e < 8; ++e)
      pk[e] = (short)f2bf(tile2[jt_loc * 32 + (l >> 4) * 8 + e][head * 32 + d]);
    const int bh_g = batch * H + by * 2 + head;
    *(short8v*)(hTbF + ((size_t)(bh_g * 32 + jt0 + jt_loc) * 64 + l) * 16 + half * 8) = pk;
  }
}

// ---------------------------------------------------------------------------
// K2: MFMA aggregation, 2-way j-split (unchanged from round 8).
// ---------------------------------------------------------------------------
__global__ __launch_bounds__(256) void gat_agg(
    const uint* __restrict__ bitsT, const float* __restrict__ siT,
    const float* __restrict__ sjT, const ushort* __restrict__ hTbF,
    float* __restrict__ out) {
  __shared__ float part[2][64][13];  // [iw][lane][12], padded
  const int t = threadIdx.x;
  const int lane = t & 63, w = t >> 6;
  const int iw = w & 1, jq = w >> 1;
  const int bid = blockIdx.x;
  const int work = ((bid & 7) << 8) + (bid >> 3);  // XCD swizzle (2048 = 8*256)
  const int bh = work >> 5;
  const int itg = work & 31;
  const int b = bh >> 3, hh = bh & 7;
  const int i0 = itg * 32 + iw * 16;
  const int la = lane & 15, g = lane >> 4;
  const int iA = i0 + la;

  const float si_r = siT[(size_t)bh * N + iA];
  const uint* btp = bitsT + (size_t)b * 32 * N + (size_t)jq * 16 * N + iA;
  const float* sjp = sjT + (size_t)bh * N + jq * 512 + g * 8;
  const ushort* hp = hTbF + (size_t)bh * 32768 + (size_t)jq * 16384 + lane * 16;

  f32x4 acc0 = {0.f, 0.f, 0.f, 0.f}, acc1 = {0.f, 0.f, 0.f, 0.f};
  f32x4 accl = {0.f, 0.f, 0.f, 0.f};
  short8v ones;
#pragma unroll
  for (int e = 0; e < 8; ++e) ones[e] = (short)0x3F80;  // bf16(1.0)

  uint bits0, bits1;
  float4 sjA0, sjB0, sjA1, sjB1;
  short8v b00, b10, b01, b11;

#define AGG_LOAD(S, JT)                                      \
  bits##S = btp[(size_t)(JT)*1024];                          \
  sjA##S = *(const float4*)(sjp + (JT) * 32);                \
  sjB##S = *(const float4*)(sjp + (JT) * 32 + 4);            \
  b0##S = *(const short8v*)(hp + (size_t)(JT)*1024);         \
  b1##S = *(const short8v*)(hp + (size_t)(JT)*1024 + 8);

#define AGG_COMP(S)                                                           \
  {                                                                           \
    const uint byte_ = (bits##S >> (g * 8)) & 0xffu;                          \
    const float sjv[8] = {sjA##S.x, sjA##S.y, sjA##S.z, sjA##S.w,             \
                          sjB##S.x, sjB##S.y, sjB##S.z, sjB##S.w};            \
    short8v af;                                                               \
    _Pragma("unroll") for (int e = 0; e < 8; ++e) {                           \
      float s = si_r + sjv[e];                                                \
      s = fmaxf(s, 0.2f * s);                                                 \
      s = ((byte_ >> e) & 1u) ? s : -INFINITY;                                \
      af[e] = (short)f2bf(__builtin_amdgcn_exp2f(s));                         \
    }                                                                         \
    __builtin_amdgcn_s_setprio(1);                                            \
    acc0 = __builtin_amdgcn_mfma_f32_16x16x32_bf16(af, b0##S, acc0, 0, 0, 0); \
    acc1 = __builtin_amdgcn_mfma_f32_16x16x32_bf16(af, b1##S, acc1, 0, 0, 0); \
    accl = __builtin_amdgcn_mfma_f32_16x16x32_bf16(af, ones, accl, 0, 0, 0);  \
    __builtin_amdgcn_s_setprio(0);                                            \
  }

  AGG_LOAD(0, 0)
  AGG_LOAD(1, 1)
#pragma unroll
  for (int jt = 0; jt < 16; jt += 2) {
    AGG_COMP(0)
    if (jt + 2 < 16) { AGG_LOAD(0, jt + 2) }
    AGG_COMP(1)
    if (jt + 3 < 16) { AGG_LOAD(1, jt + 3) }
  }
#undef AGG_LOAD
#undef AGG_COMP

  if (jq == 1) {
    float* p = part[iw][lane];
#pragma unroll
    for (int k = 0; k < 4; ++k) {
      p[k] = acc0[k];
      p[4 + k] = acc1[k];
      p[8 + k] = accl[k];
    }
  }
  __syncthreads();
  if (jq == 0) {
    const float* p = part[iw][lane];
#pragma unroll
    for (int k = 0; k < 4; ++k) {
      acc0[k] += p[k];
      acc1[k] += p[4 + k];
      accl[k] += p[8 + k];
    }
    float* op = out + ((size_t)(b * N + i0)) * OUTD + hh * D;
#pragma unroll
    for (int r = 0; r < 4; ++r) {
      const int ic = g * 4 + r;
      const float li = accl[r];  // row-sum (identical across cols)
      float v0 = acc0[r] / li;
      v0 = v0 > 0.f ? v0 : expm1f(v0);
      op[(size_t)ic * OUTD + la] = v0;
      float v1 = acc1[r] / li;
      v1 = v1 > 0.f ? v1 : expm1f(v1);
      op[(size_t)ic * OUTD + 16 + la] = v1;
    }
  }
}

extern "C" void kernel_launch(void* const* d_in, const int* in_sizes, int n_in,
                              void* d_out, int out_size, void* d_ws, size_t ws_size,
                              hipStream_t stream) {
  const float* x = (const float*)d_in[0];
  const int* adj = (const int*)d_in[1];
  const float* W = (const float*)d_in[2];
  const float* a = (const float*)d_in[3];
  float* out = (float*)d_out;

  float* ws = (float*)d_ws;
  float* siT = ws;                                   // 65,536 f32
  float* sjT = siT + (size_t)B * N * H;              // 65,536 f32
  uint* bitsT = (uint*)(sjT + (size_t)B * N * H);    // 262,144 u32 (1 MB)
  ushort* hTbF = (ushort*)(bitsT + (size_t)B * 32 * N);  // 2,097,152 bf16 (4 MB)

  gat_k1<<<512 + 2048, 256, 0, stream>>>(x, W, a, adj, bitsT, siT, sjT, hTbF);
  gat_agg<<<2048, 256, 0, stream>>>(bitsT, siT, sjT, hTbF, out);
}